// Round 1
// baseline (1207.918 us; speedup 1.0000x reference)
//
#include <hip/hip_runtime.h>
#include <cstdint>
#include <cstddef>

#define BATCH 8
#define NN 2048
#define RTOT 16384   // BATCH*NN
#define KCL 100
#define CAP 192      // ELL row capacity (mean nnz/row ~102, sigma ~10)

// ---------------- workspace layout (offsets in floats) ----------------
static constexpr size_t OF_BKT_L1 = 0;            // 64*60*2  = 7680
static constexpr size_t OF_BKT_L2 = 7680;         // 7680
static constexpr size_t OF_BKT_L3 = 15360;        // 64*130*2 = 16640
static constexpr size_t OF_BKT_S2A = 32000;       // 8*30*2 = 480
static constexpr size_t OF_BKT_S2B = 32480;
static constexpr size_t OF_BKT_S2C = 32960;
static constexpr size_t OF_P1X    = 33440;        // 8*100*30 = 24000
static constexpr size_t OF_P1ADJ  = 57440;        // 8*100*100 = 80000
static constexpr size_t ZERO_FLOATS = 137440;     // everything above gets memset(0)
static constexpr size_t OF_ELLV   = 137472;                   // 16384*192 = 3145728
static constexpr size_t OF_ELLC   = OF_ELLV + 3145728;        // u16: 3145728 u16 = 1572864 floats
static constexpr size_t OF_ROWLEN = OF_ELLC + 1572864;        // int 16384
static constexpr size_t OF_DINVW  = OF_ROWLEN + 16384;
static constexpr size_t OF_DINVB  = OF_DINVW + 16384;
static constexpr size_t OF_HW     = OF_DINVB + 16384;         // 16384*30
static constexpr size_t OF_HB     = OF_HW + 491520;           // 16384*100 (later reused as softmax S)
static constexpr size_t OF_ZW     = OF_HB + 1638400;          // 16384*30
static constexpr size_t OF_ZB     = OF_ZW + 491520;           // 16384*100 (later reused as As = adj@s)
static constexpr size_t OF_X11    = OF_ZB + 1638400;
static constexpr size_t OF_X12    = OF_X11 + 491520;
static constexpr size_t OF_X13    = OF_X12 + 491520;
static constexpr size_t OF_S11    = OF_X13 + 491520;
static constexpr size_t OF_S12    = OF_S11 + 491520;
static constexpr size_t OF_AC     = OF_S12 + 491520;          // 9 slots * 256 floats (a[C], shift[C])
static constexpr size_t OF_A2     = OF_AC + 2304;             // 8*100*100
static constexpr size_t OF_Z21    = OF_A2 + 80000;            // 8*100*30
static constexpr size_t OF_Z22    = OF_Z21 + 24000;
static constexpr size_t OF_Z23    = OF_Z22 + 24000;
static constexpr size_t OF_X21    = OF_Z23 + 24000;
static constexpr size_t OF_X22    = OF_X21 + 24000;
static constexpr size_t OF_PARTMAX= OF_X22 + 24000;           // 8*8*90
static constexpr size_t OF_X1OUT  = OF_PARTMAX + 5760;        // 720
static constexpr size_t OF_X2OUT  = OF_X1OUT + 720;           // 720

// ---------------- kernels ----------------

// One pass over adj: build ELL (val fp32 + col u16), weighted degree, binary degree.
__global__ __launch_bounds__(256) void k_build_ell(
    const float* __restrict__ adj, float* __restrict__ ellv,
    unsigned short* __restrict__ ellc, int* __restrict__ rowlen,
    float* __restrict__ dinvw, float* __restrict__ dinvb)
{
  int r = blockIdx.x;
  const float* row = adj + (size_t)r * NN;
  __shared__ int cnt;
  __shared__ float wsum[4];
  int t = threadIdx.x, lane = t & 63;
  if (t == 0) cnt = 0;
  __syncthreads();
  float sum = 0.f;
  size_t base = (size_t)r * CAP;
  for (int h = 0; h < 2; ++h) {
    int col0 = h * 1024 + t * 4;
    float4 v4 = *(const float4*)(row + col0);
    float vv[4] = {v4.x, v4.y, v4.z, v4.w};
#pragma unroll
    for (int k = 0; k < 4; ++k) {
      float v = vv[k];
      sum += v;
      bool p = (v != 0.f);
      unsigned long long m = __ballot(p);
      int c_ = __popcll(m);
      int bw = 0;
      if (lane == 0) bw = atomicAdd(&cnt, c_);
      bw = __shfl(bw, 0);
      if (p) {
        int pos = bw + __popcll(m & ((1ull << lane) - 1ull));
        if (pos < CAP) { ellv[base + pos] = v; ellc[base + pos] = (unsigned short)(col0 + k); }
      }
    }
  }
  for (int o = 32; o > 0; o >>= 1) sum += __shfl_down(sum, o);
  if (lane == 0) wsum[t >> 6] = sum;
  __syncthreads();
  if (t == 0) {
    float tot = wsum[0] + wsum[1] + wsum[2] + wsum[3];
    int n = cnt; if (n > CAP) n = CAP;
    int nnz = n;
    while ((n & 3) && n < CAP) { ellv[base + n] = 0.f; ellc[base + n] = 0; ++n; }
    rowlen[r] = n;
    dinvw[r] = rsqrtf(tot + 1.f);          // deg_w = rowsum + 1 (self loop)
    dinvb[r] = rsqrtf((float)nnz + 1.f);   // deg_b = nnz + 1
  }
}

// H1 = x @ W_in[0/1], pre-scaled by dinv
__global__ __launch_bounds__(256) void k_h1(
    const float* __restrict__ x, const float* __restrict__ Win,
    const float* __restrict__ dinvw, const float* __restrict__ dinvb,
    float* __restrict__ Hw, float* __restrict__ Hb)
{
  int t = blockIdx.x * 256 + threadIdx.x;
  if (t >= RTOT * 30) return;
  int i = t / 30, c = t % 30;
  float x0 = x[i*3], x1 = x[i*3+1], x2 = x[i*3+2];
  float hw = x0*Win[c]    + x1*Win[30+c]  + x2*Win[60+c];
  float hb = x0*Win[90+c] + x1*Win[120+c] + x2*Win[150+c];
  Hw[t] = dinvw[i]*hw;
  Hb[t] = dinvb[i]*hb;
}

// ELL SpMM: out[i,c] = scale[i]*( sum_nz w*H[col,c] + self? H[i,c] ), optional BN-stats atomics
template<int C, int GROUP, bool WEIGHTED, bool SELFLOOP, bool SCALED, bool STATS>
__global__ __launch_bounds__(256) void k_spmm(
    const float* __restrict__ H, const float* __restrict__ ellv,
    const unsigned short* __restrict__ ellc, const int* __restrict__ rowlen,
    const float* __restrict__ scale, float* __restrict__ out,
    float* __restrict__ bkt, int choff, int ctot)
{
  constexpr int RPB = 256 / GROUP;
  int g = threadIdx.x / GROUP, c = threadIdx.x % GROUP;
  int row = blockIdx.x * RPB + g;
  if (c >= C) return;
  int len = rowlen[row];
  size_t base = (size_t)row * CAP;
  const float* Hbase = H + (size_t)(row >> 11) * ((size_t)NN * C);
  float acc = 0.f;
  for (int n = 0; n < len; n += 4) {
    int c0 = ellc[base+n], c1 = ellc[base+n+1], c2 = ellc[base+n+2], c3 = ellc[base+n+3];
    float v0 = ellv[base+n], v1 = ellv[base+n+1], v2 = ellv[base+n+2], v3 = ellv[base+n+3];
    float h0 = Hbase[(size_t)c0*C+c], h1 = Hbase[(size_t)c1*C+c];
    float h2 = Hbase[(size_t)c2*C+c], h3 = Hbase[(size_t)c3*C+c];
    if (WEIGHTED) acc += v0*h0 + v1*h1 + v2*h2 + v3*h3;
    else acc += (v0>0.f?h0:0.f) + (v1>0.f?h1:0.f) + (v2>0.f?h2:0.f) + (v3>0.f?h3:0.f);
  }
  if (SELFLOOP) acc += H[(size_t)row*C + c];
  float z = SCALED ? scale[row]*acc : acc;
  out[(size_t)row*C + c] = z;
  if (STATS) {
    float* p = bkt + ((size_t)(blockIdx.x & 63)*ctot + choff + c)*2;
    atomicAdd(p, z);
    atomicAdd(p+1, z*z);
  }
}

// reduce stat buckets -> per-channel BN scale a and shift
__global__ void k_finalize(const float* __restrict__ bkt, int nbkt, int ctot,
    float count, const float* gA, const float* bA, int cA, float* outA,
    const float* gB, const float* bB, int cB, float* outB)
{
  int c = threadIdx.x;
  if (c >= ctot) return;
  float s1 = 0.f, s2 = 0.f;
  for (int b = 0; b < nbkt; ++b) {
    s1 += bkt[((size_t)b*ctot + c)*2];
    s2 += bkt[((size_t)b*ctot + c)*2 + 1];
  }
  float mean = s1 / count;
  float var  = s2 / count - mean*mean;
  float inv  = rsqrtf(var + 1e-5f);
  if (c < cA) { float a = gA[c]*inv; outA[c] = a; outA[cA + c] = bA[c] - mean*a; }
  else { int cc = c - cA; float a = gB[cc]*inv; outB[cc] = a; outB[cB + cc] = bB[cc] - mean*a; }
}

// apply BN -> store x/s -> next-layer weight GEMM, pre-scaled by dinv
__global__ __launch_bounds__(256) void k_apply_gemm(
    const float* __restrict__ Zw, const float* __restrict__ acW,
    float* __restrict__ xst, const float* __restrict__ Ww,
    float* __restrict__ Hwo, const float* __restrict__ dinvw,
    const float* __restrict__ Zb, const float* __restrict__ acB,
    float* __restrict__ sst, const float* __restrict__ Wb,
    float* __restrict__ Hbo, const float* __restrict__ dinvb, int coutb)
{
  int ct = 30 + coutb;
  int t = blockIdx.x * 256 + threadIdx.x;
  if (t >= RTOT * ct) return;
  int i = t / ct, c = t % ct;
  if (c < 30) {
    float xc = acW[c]*Zw[i*30+c] + acW[30+c];
    xst[i*30+c] = xc;
    float acc = 0.f;
    for (int k = 0; k < 30; ++k) {
      float xv = acW[k]*Zw[i*30+k] + acW[30+k];
      acc += xv * Ww[k*30+c];
    }
    Hwo[i*30+c] = dinvw[i]*acc;
  } else {
    int cc = c - 30;
    if (cc < 30) sst[i*30+cc] = acB[cc]*Zb[i*30+cc] + acB[30+cc];
    float acc = 0.f;
    for (int k = 0; k < 30; ++k) {
      float sv = acB[k]*Zb[i*30+k] + acB[30+k];
      acc += sv * Wb[k*coutb + cc];
    }
    Hbo[(size_t)i*coutb + cc] = dinvb[i]*acc;
  }
}

// BN(Z3w)->x13 store; s13=BN(Z3b); s1 = [s11|s12|s13] @ Wfc + bfc  (raw, softmax later)
__global__ __launch_bounds__(256) void k_fcpool(
    const float* __restrict__ Zw3, const float* __restrict__ acW3,
    const float* __restrict__ Zb3, const float* __restrict__ acB3,
    const float* __restrict__ s11, const float* __restrict__ s12,
    const float* __restrict__ Wfc, const float* __restrict__ bfc,
    float* __restrict__ x13, float* __restrict__ s1out)
{
  __shared__ float feat[64][160];
  __shared__ float Wl[40][100];
  int t = threadIdx.x;
  int g0 = blockIdx.x * 64;
  for (int idx = t; idx < 64*160; idx += 256) {
    int l = idx / 160, c = idx % 160;
    int g = g0 + l;
    float v;
    if (c < 30) v = s11[g*30 + c];
    else if (c < 60) v = s12[g*30 + (c-30)];
    else { int k = c - 60; v = acB3[k]*Zb3[(size_t)g*100 + k] + acB3[100 + k]; }
    feat[l][c] = v;
  }
  for (int idx = t; idx < 64*30; idx += 256) {
    int l = idx/30, c = idx%30;
    int g = g0 + l;
    x13[g*30+c] = acW3[c]*Zw3[g*30+c] + acW3[30+c];
  }
  int np = t >> 3, kg = t & 7;
  int n0 = np*2, n1 = np*2 + 1;
  int kbase = kg*12 + (kg < 4 ? kg : 4);
  int klen  = kg < 4 ? 13 : 12;
  float a0[13], a1[13];
#pragma unroll
  for (int j = 0; j < 13; ++j) { a0[j] = 0.f; a1[j] = 0.f; }
  for (int ch = 0; ch < 4; ++ch) {
    __syncthreads();
    for (int idx = t; idx < 4000; idx += 256) {
      int r = idx/100, j = idx%100;
      Wl[r][j] = Wfc[(ch*40 + r)*100 + j];
    }
    __syncthreads();
    for (int kk = 0; kk < 40; ++kk) {
      float f0 = feat[n0][ch*40+kk];
      float f1 = feat[n1][ch*40+kk];
#pragma unroll
      for (int j = 0; j < 13; ++j) {
        if (j < klen) {
          float w = Wl[kk][kbase + j];
          a0[j] += f0*w; a1[j] += f1*w;
        }
      }
    }
  }
  for (int j = 0; j < klen; ++j) {
    int k = kbase + j;
    s1out[(size_t)(g0+n0)*100 + k] = a0[j] + bfc[k];
    s1out[(size_t)(g0+n1)*100 + k] = a1[j] + bfc[k];
  }
}

// in-place softmax over 100 clusters, one wave per node
__global__ __launch_bounds__(256) void k_softmax(float* __restrict__ S)
{
  int w = threadIdx.x >> 6, lane = threadIdx.x & 63;
  int node = blockIdx.x * 4 + w;
  float* p = S + (size_t)node * 100;
  float v0 = p[lane];
  float v1 = lane < 36 ? p[64 + lane] : -3.4e38f;
  float m = fmaxf(v0, v1);
  for (int o = 32; o; o >>= 1) m = fmaxf(m, __shfl_xor(m, o));
  float e0 = expf(v0 - m);
  float e1 = lane < 36 ? expf(v1 - m) : 0.f;
  float s = e0 + e1;
  for (int o = 32; o; o >>= 1) s += __shfl_xor(s, o);
  float r = 1.f / s;
  p[lane] = e0 * r;
  if (lane < 36) p[64 + lane] = e1 * r;
}

// p1x = s^T x13, p1adj = s^T (adj@s): split-K over node chunks, atomics
__global__ __launch_bounds__(256) void k_pool_gemm(
    const float* __restrict__ S, const float* __restrict__ x13,
    const float* __restrict__ As, float* __restrict__ p1x, float* __restrict__ p1adj)
{
  __shared__ float sL[64][100];
  __shared__ float xL[64][132];
  int t = threadIdx.x;
  int b = blockIdx.x >> 5, chunk = blockIdx.x & 31;
  int g0 = b * 2048 + chunk * 64;
  for (int idx = t; idx < 64*100; idx += 256) {
    int l = idx/100, k = idx%100;
    sL[l][k] = S[(size_t)(g0+l)*100 + k];
  }
  for (int idx = t; idx < 64*130; idx += 256) {
    int l = idx/130, d = idx%130;
    xL[l][d] = d < 30 ? x13[(g0+l)*30 + d] : As[(size_t)(g0+l)*100 + (d-30)];
  }
  __syncthreads();
  if (t < 250) {
    int kt = t/10, dt = t%10;
    int k0 = kt*4, d0 = dt*13;
    float acc[4][13];
#pragma unroll
    for (int a = 0; a < 4; ++a)
#pragma unroll
      for (int j = 0; j < 13; ++j) acc[a][j] = 0.f;
    for (int kk = 0; kk < 64; ++kk) {
      float sv[4];
#pragma unroll
      for (int a = 0; a < 4; ++a) sv[a] = sL[kk][k0+a];
#pragma unroll
      for (int j = 0; j < 13; ++j) {
        float xv = xL[kk][d0+j];
#pragma unroll
        for (int a = 0; a < 4; ++a) acc[a][j] += sv[a]*xv;
      }
    }
    for (int a = 0; a < 4; ++a)
      for (int j = 0; j < 13; ++j) {
        int k = k0 + a, d = d0 + j;
        if (d < 30) atomicAdd(&p1x[((size_t)b*100 + k)*30 + d], acc[a][j]);
        else atomicAdd(&p1adj[((size_t)b*100 + k)*100 + (d-30)], acc[a][j]);
      }
  }
}

// gcn-normalize pooled adjacency
__global__ __launch_bounds__(256) void k_norm_a2(const float* __restrict__ p1adj, float* __restrict__ A2)
{
  __shared__ float Ah[100*100];
  __shared__ float dl[100];
  int b = blockIdx.x, t = threadIdx.x;
  for (int idx = t; idx < 10000; idx += 256) {
    float v = p1adj[(size_t)b*10000 + idx];
    int i = idx/100, j = idx%100;
    if (i == j && v == 0.f) v = 1.f;  // add self-loop only where diag==0
    Ah[idx] = v;
  }
  __syncthreads();
  if (t < 100) {
    float s = 0.f;
    for (int j = 0; j < 100; ++j) s += Ah[t*100 + j];
    dl[t] = s > 0.f ? rsqrtf(s) : 0.f;
  }
  __syncthreads();
  for (int idx = t; idx < 10000; idx += 256) {
    int i = idx/100, j = idx%100;
    A2[(size_t)b*10000 + idx] = dl[i]*dl[j]*Ah[idx];
  }
}

// stage-2 GCN layer: (optional BN-apply of Zprev -> Xin, store) then Z = A2 @ (Xin @ W), stats
__global__ __launch_bounds__(256) void k_s2layer(
    const float* __restrict__ Xraw, const float* __restrict__ Zprev,
    const float* __restrict__ ac, float* __restrict__ xst,
    const float* __restrict__ Wm, const float* __restrict__ A2,
    float* __restrict__ Zout, float* __restrict__ bkt)
{
  __shared__ float Xl[100*30];
  __shared__ float Tl[100*30];
  __shared__ float Al[100*100];
  int b = blockIdx.x, t = threadIdx.x;
  for (int idx = t; idx < 3000; idx += 256) {
    float v;
    if (ac == nullptr) v = Xraw[(size_t)b*3000 + idx];
    else {
      int c = idx % 30;
      v = ac[c]*Zprev[(size_t)b*3000 + idx] + ac[30+c];
      xst[(size_t)b*3000 + idx] = v;
    }
    Xl[idx] = v;
  }
  for (int idx = t; idx < 10000; idx += 256) Al[idx] = A2[(size_t)b*10000 + idx];
  __syncthreads();
  for (int idx = t; idx < 3000; idx += 256) {
    int i = idx/30, c = idx%30;
    float acc = 0.f;
    for (int k = 0; k < 30; ++k) acc += Xl[i*30+k]*Wm[k*30+c];
    Tl[idx] = acc;
  }
  __syncthreads();
  for (int idx = t; idx < 3000; idx += 256) {
    int i = idx/30, c = idx%30;
    float acc = 0.f;
    for (int j = 0; j < 100; ++j) acc += Al[i*100+j]*Tl[j*30+c];
    Zout[(size_t)b*3000 + idx] = acc;
    float* p = bkt + ((size_t)b*30 + c)*2;
    atomicAdd(p, acc);
    atomicAdd(p+1, acc*acc);
  }
}

// stage-1 per-segment column max of [x11|x12|x13]
__global__ __launch_bounds__(128) void k_max1(
    const float* __restrict__ x11, const float* __restrict__ x12,
    const float* __restrict__ x13, float* __restrict__ pm)
{
  int b = blockIdx.x >> 3, seg = blockIdx.x & 7;
  int c = threadIdx.x;
  if (c >= 90) return;
  const float* src = c < 30 ? x11 : (c < 60 ? x12 : x13);
  int cc = c % 30;
  int r0 = b*2048 + seg*256;
  float m = -3.4e38f;
  for (int i = 0; i < 256; ++i) m = fmaxf(m, src[(size_t)(r0+i)*30 + cc]);
  pm[(size_t)(b*8+seg)*90 + c] = m;
}

// finish maxes: x1out from partials; x2out from x21/x22/BN(Z23)
__global__ __launch_bounds__(128) void k_max2(
    const float* __restrict__ pm, const float* __restrict__ x21,
    const float* __restrict__ x22, const float* __restrict__ Z23,
    const float* __restrict__ ac23, float* __restrict__ x1out, float* __restrict__ x2out)
{
  int b = blockIdx.x, c = threadIdx.x;
  if (c >= 90) return;
  float m = -3.4e38f;
  for (int s = 0; s < 8; ++s) m = fmaxf(m, pm[(size_t)(b*8+s)*90 + c]);
  x1out[b*90+c] = m;
  float m2 = -3.4e38f;
  int cc = c % 30;
  for (int i = 0; i < 100; ++i) {
    float v;
    if (c < 30) v = x21[(size_t)b*3000 + i*30 + cc];
    else if (c < 60) v = x22[(size_t)b*3000 + i*30 + cc];
    else v = ac23[cc]*Z23[(size_t)b*3000 + i*30 + cc] + ac23[30+cc];
    m2 = fmaxf(m2, v);
  }
  x2out[b*90+c] = m2;
}

__global__ __launch_bounds__(512) void k_mlp(
    const float* __restrict__ x1out, const float* __restrict__ x2out,
    const float* __restrict__ W1, const float* __restrict__ b1,
    const float* __restrict__ W2, const float* __restrict__ b2,
    float* __restrict__ out)
{
  __shared__ float hh[400];
  int t = threadIdx.x;
  if (t < 400) {
    int b = t/50, j = t%50;
    float acc = b1[j];
    for (int k = 0; k < 90; ++k) acc += x1out[b*90+k]*W1[k*50+j];
    for (int k = 0; k < 90; ++k) acc += x2out[b*90+k]*W1[(90+k)*50+j];
    hh[t] = fmaxf(acc, 0.f);
  }
  __syncthreads();
  if (t < 48) {
    int b = t/6, o = t%6;
    float acc = b2[o];
    for (int j = 0; j < 50; ++j) acc += hh[b*50+j]*W2[j*6+o];
    out[b*6+o] = acc;
  }
}

// ---------------- launcher ----------------
extern "C" void kernel_launch(void* const* d_in, const int* in_sizes, int n_in,
                              void* d_out, int out_size, void* d_ws, size_t ws_size,
                              hipStream_t stream)
{
  const float* x    = (const float*)d_in[0];
  const float* adj  = (const float*)d_in[1];
  const float* Win  = (const float*)d_in[2];
  const float* W3030= (const float*)d_in[3];
  const float* Wp13 = (const float*)d_in[4];
  // d_in[5]=b30, d_in[6]=b100: cancel through training-mode BN -> unused
  const float* Wfc  = (const float*)d_in[7];
  const float* bfc  = (const float*)d_in[8];
  const float* W1   = (const float*)d_in[9];
  const float* b1   = (const float*)d_in[10];
  const float* W2   = (const float*)d_in[11];
  const float* b2   = (const float*)d_in[12];
  const float* g30  = (const float*)d_in[13];
  const float* be30 = (const float*)d_in[14];
  const float* g100 = (const float*)d_in[15];
  const float* be100= (const float*)d_in[16];
  float* out = (float*)d_out;

  float* wsf = (float*)d_ws;
  float* bktL1 = wsf + OF_BKT_L1;
  float* bktL2 = wsf + OF_BKT_L2;
  float* bktL3 = wsf + OF_BKT_L3;
  float* bktS2a = wsf + OF_BKT_S2A;
  float* bktS2b = wsf + OF_BKT_S2B;
  float* bktS2c = wsf + OF_BKT_S2C;
  float* p1x   = wsf + OF_P1X;
  float* p1adj = wsf + OF_P1ADJ;
  float* ellv  = wsf + OF_ELLV;
  unsigned short* ellc = (unsigned short*)(wsf + OF_ELLC);
  int*   rowlen = (int*)(wsf + OF_ROWLEN);
  float* dinvw = wsf + OF_DINVW;
  float* dinvb = wsf + OF_DINVB;
  float* Hw = wsf + OF_HW;
  float* Hb = wsf + OF_HB;      // later: softmax S
  float* Zw = wsf + OF_ZW;
  float* Zb = wsf + OF_ZB;      // later: As = adj@s
  float* x11 = wsf + OF_X11;
  float* x12 = wsf + OF_X12;
  float* x13 = wsf + OF_X13;
  float* s11 = wsf + OF_S11;
  float* s12 = wsf + OF_S12;
  float* acw1 = wsf + OF_AC + 0;
  float* acb1 = wsf + OF_AC + 256;
  float* acw2 = wsf + OF_AC + 512;
  float* acb2 = wsf + OF_AC + 768;
  float* acw3 = wsf + OF_AC + 1024;
  float* acb3 = wsf + OF_AC + 1280;
  float* acs1 = wsf + OF_AC + 1536;
  float* acs2 = wsf + OF_AC + 1792;
  float* acs3 = wsf + OF_AC + 2048;
  float* A2  = wsf + OF_A2;
  float* Z21 = wsf + OF_Z21;
  float* Z22 = wsf + OF_Z22;
  float* Z23 = wsf + OF_Z23;
  float* x21 = wsf + OF_X21;
  float* x22 = wsf + OF_X22;
  float* partmax = wsf + OF_PARTMAX;
  float* x1out = wsf + OF_X1OUT;
  float* x2out = wsf + OF_X2OUT;

  hipMemsetAsync(wsf, 0, ZERO_FLOATS * sizeof(float), stream);

  k_build_ell<<<RTOT, 256, 0, stream>>>(adj, ellv, ellc, rowlen, dinvw, dinvb);
  k_h1<<<(RTOT*30)/256, 256, 0, stream>>>(x, Win, dinvw, dinvb, Hw, Hb);

  // level 1
  k_spmm<30,32,true ,true,true,true ><<<2048, 256, 0, stream>>>(Hw, ellv, ellc, rowlen, dinvw, Zw, bktL1, 0, 60);
  k_spmm<30,32,false,true,true,true ><<<2048, 256, 0, stream>>>(Hb, ellv, ellc, rowlen, dinvb, Zb, bktL1, 30, 60);
  k_finalize<<<1, 256, 0, stream>>>(bktL1, 64, 60, 16384.f, g30+0,  be30+0,  30, acw1, g30+90,  be30+90,  30, acb1);
  k_apply_gemm<<<(RTOT*60)/256, 256, 0, stream>>>(Zw, acw1, x11, W3030+0,   Hw, dinvw, Zb, acb1, s11, W3030+2*900, Hb, dinvb, 30);

  // level 2
  k_spmm<30,32,true ,true,true,true ><<<2048, 256, 0, stream>>>(Hw, ellv, ellc, rowlen, dinvw, Zw, bktL2, 0, 60);
  k_spmm<30,32,false,true,true,true ><<<2048, 256, 0, stream>>>(Hb, ellv, ellc, rowlen, dinvb, Zb, bktL2, 30, 60);
  k_finalize<<<1, 256, 0, stream>>>(bktL2, 64, 60, 16384.f, g30+30, be30+30, 30, acw2, g30+120, be30+120, 30, acb2);
  k_apply_gemm<<<(RTOT*130)/256, 256, 0, stream>>>(Zw, acw2, x12, W3030+900, Hw, dinvw, Zb, acb2, s12, Wp13,        Hb, dinvb, 100);

  // level 3
  k_spmm<30,32,true ,true,true,true  ><<<2048, 256, 0, stream>>>(Hw, ellv, ellc, rowlen, dinvw, Zw, bktL3, 0, 130);
  k_spmm<100,128,false,true,true,true><<<8192, 256, 0, stream>>>(Hb, ellv, ellc, rowlen, dinvb, Zb, bktL3, 30, 130);
  k_finalize<<<1, 256, 0, stream>>>(bktL3, 64, 130, 16384.f, g30+60, be30+60, 30, acw3, g100, be100, 100, acb3);

  // pooling assignment
  k_fcpool<<<256, 256, 0, stream>>>(Zw, acw3, Zb, acb3, s11, s12, Wfc, bfc, x13, Hb /* S */);
  k_softmax<<<4096, 256, 0, stream>>>(Hb);
  k_spmm<100,128,true,false,false,false><<<8192, 256, 0, stream>>>(Hb, ellv, ellc, rowlen, nullptr, Zb /* As */, nullptr, 0, 0);
  k_pool_gemm<<<256, 256, 0, stream>>>(Hb, x13, Zb, p1x, p1adj);
  k_norm_a2<<<BATCH, 256, 0, stream>>>(p1adj, A2);

  // stage 2
  k_s2layer<<<BATCH, 256, 0, stream>>>(p1x, nullptr, nullptr, nullptr, W3030+3*900, A2, Z21, bktS2a);
  k_finalize<<<1, 256, 0, stream>>>(bktS2a, 8, 30, 800.f, g30+150, be30+150, 30, acs1, nullptr, nullptr, 0, nullptr);
  k_s2layer<<<BATCH, 256, 0, stream>>>(nullptr, Z21, acs1, x21, W3030+4*900, A2, Z22, bktS2b);
  k_finalize<<<1, 256, 0, stream>>>(bktS2b, 8, 30, 800.f, g30+180, be30+180, 30, acs2, nullptr, nullptr, 0, nullptr);
  k_s2layer<<<BATCH, 256, 0, stream>>>(nullptr, Z22, acs2, x22, W3030+5*900, A2, Z23, bktS2c);
  k_finalize<<<1, 256, 0, stream>>>(bktS2c, 8, 30, 800.f, g30+210, be30+210, 30, acs3, nullptr, nullptr, 0, nullptr);

  // readout
  k_max1<<<64, 128, 0, stream>>>(x11, x12, x13, partmax);
  k_max2<<<BATCH, 128, 0, stream>>>(partmax, x21, x22, Z23, acs3, x1out, x2out);
  k_mlp<<<1, 512, 0, stream>>>(x1out, x2out, W1, b1, W2, b2, out);
}

// Round 2
// 977.363 us; speedup vs baseline: 1.2359x; 1.2359x over previous
//
#include <hip/hip_runtime.h>
#include <cstdint>
#include <cstddef>

#define BATCH 8
#define NN 2048
#define RTOT 16384   // BATCH*NN
#define KCL 100
#define CAP 192      // ELL row capacity (mean nnz/row ~102, sigma ~10)

// ---------------- workspace layout (offsets in floats) ----------------
static constexpr size_t OF_BKT_L1 = 0;            // 64*60*2  = 7680
static constexpr size_t OF_BKT_L2 = 7680;         // 7680
static constexpr size_t OF_BKT_L3 = 15360;        // 64*130*2 = 16640
static constexpr size_t OF_BKT_S2A = 32000;       // 8*30*2 = 480
static constexpr size_t OF_BKT_S2B = 32480;
static constexpr size_t OF_BKT_S2C = 32960;
static constexpr size_t OF_P1X    = 33440;        // 8*100*30 = 24000
static constexpr size_t OF_P1ADJ  = 57440;        // 8*100*100 = 80000
static constexpr size_t OF_ELLV   = 137472;                   // 16384*192 = 3145728
static constexpr size_t OF_ELLC   = OF_ELLV + 3145728;        // u16: 3145728 u16 = 1572864 floats
static constexpr size_t OF_ROWLEN = OF_ELLC + 1572864;        // int 16384
static constexpr size_t OF_DINVW  = OF_ROWLEN + 16384;
static constexpr size_t OF_DINVB  = OF_DINVW + 16384;
static constexpr size_t OF_HW     = OF_DINVB + 16384;         // 16384*30
static constexpr size_t OF_HB     = OF_HW + 491520;           // 16384*100 (later reused as softmax S)
static constexpr size_t OF_ZW     = OF_HB + 1638400;          // 16384*30
static constexpr size_t OF_ZB     = OF_ZW + 491520;           // 16384*100 (later reused as As = adj@s)
static constexpr size_t OF_X11    = OF_ZB + 1638400;
static constexpr size_t OF_X12    = OF_X11 + 491520;
static constexpr size_t OF_X13    = OF_X12 + 491520;
static constexpr size_t OF_S11    = OF_X13 + 491520;          // s11+s12 contiguous: reused as pool partials (832000 <= 983040)
static constexpr size_t OF_S12    = OF_S11 + 491520;
static constexpr size_t OF_AC     = OF_S12 + 491520;          // 9 slots * 256 floats (a[C], shift[C])
static constexpr size_t OF_A2     = OF_AC + 2304;             // 8*100*100
static constexpr size_t OF_Z21    = OF_A2 + 80000;            // 8*100*30
static constexpr size_t OF_Z22    = OF_Z21 + 24000;
static constexpr size_t OF_Z23    = OF_Z22 + 24000;
static constexpr size_t OF_X21    = OF_Z23 + 24000;
static constexpr size_t OF_X22    = OF_X21 + 24000;
static constexpr size_t OF_PARTMAX= OF_X22 + 24000;           // 8*8*90
static constexpr size_t OF_X1OUT  = OF_PARTMAX + 5760;        // 720
static constexpr size_t OF_X2OUT  = OF_X1OUT + 720;           // 720

// ---------------- kernels ----------------

// One pass over adj: build ELL (val fp32 + col u16), weighted degree, binary degree.
__global__ __launch_bounds__(256) void k_build_ell(
    const float* __restrict__ adj, float* __restrict__ ellv,
    unsigned short* __restrict__ ellc, int* __restrict__ rowlen,
    float* __restrict__ dinvw, float* __restrict__ dinvb)
{
  int r = blockIdx.x;
  const float* row = adj + (size_t)r * NN;
  __shared__ int cnt;
  __shared__ float wsum[4];
  int t = threadIdx.x, lane = t & 63;
  if (t == 0) cnt = 0;
  __syncthreads();
  float sum = 0.f;
  size_t base = (size_t)r * CAP;
  for (int h = 0; h < 2; ++h) {
    int col0 = h * 1024 + t * 4;
    float4 v4 = *(const float4*)(row + col0);
    float vv[4] = {v4.x, v4.y, v4.z, v4.w};
#pragma unroll
    for (int k = 0; k < 4; ++k) {
      float v = vv[k];
      sum += v;
      bool p = (v != 0.f);
      unsigned long long m = __ballot(p);
      int c_ = __popcll(m);
      int bw = 0;
      if (lane == 0) bw = atomicAdd(&cnt, c_);
      bw = __shfl(bw, 0);
      if (p) {
        int pos = bw + __popcll(m & ((1ull << lane) - 1ull));
        if (pos < CAP) { ellv[base + pos] = v; ellc[base + pos] = (unsigned short)(col0 + k); }
      }
    }
  }
  for (int o = 32; o > 0; o >>= 1) sum += __shfl_down(sum, o);
  if (lane == 0) wsum[t >> 6] = sum;
  __syncthreads();
  if (t == 0) {
    float tot = wsum[0] + wsum[1] + wsum[2] + wsum[3];
    int n = cnt; if (n > CAP) n = CAP;
    int nnz = n;
    while ((n & 3) && n < CAP) { ellv[base + n] = 0.f; ellc[base + n] = 0; ++n; }
    rowlen[r] = n;
    dinvw[r] = rsqrtf(tot + 1.f);          // deg_w = rowsum + 1 (self loop)
    dinvb[r] = rsqrtf((float)nnz + 1.f);   // deg_b = nnz + 1
  }
}

// H1 = x @ W_in[0/1], pre-scaled by dinv
__global__ __launch_bounds__(256) void k_h1(
    const float* __restrict__ x, const float* __restrict__ Win,
    const float* __restrict__ dinvw, const float* __restrict__ dinvb,
    float* __restrict__ Hw, float* __restrict__ Hb)
{
  int t = blockIdx.x * 256 + threadIdx.x;
  if (t >= RTOT * 30) return;
  int i = t / 30, c = t % 30;
  float x0 = x[i*3], x1 = x[i*3+1], x2 = x[i*3+2];
  float hw = x0*Win[c]    + x1*Win[30+c]  + x2*Win[60+c];
  float hb = x0*Win[90+c] + x1*Win[120+c] + x2*Win[150+c];
  Hw[t] = dinvw[i]*hw;
  Hb[t] = dinvb[i]*hb;
}

// ELL SpMM, flat-indexed: out[i,c] = scale[i]*( sum_nz w*H[col,c] + self? H[i,c] )
// grid covers RTOT*C exactly (C=30: 1920 blocks; C=100: 6400 blocks)
template<int C, bool WEIGHTED, bool SELFLOOP, bool SCALED>
__global__ __launch_bounds__(256) void k_spmm(
    const float* __restrict__ H, const float* __restrict__ ellv,
    const unsigned short* __restrict__ ellc, const int* __restrict__ rowlen,
    const float* __restrict__ scale, float* __restrict__ out)
{
  int gid = blockIdx.x * 256 + threadIdx.x;
  int row = gid / C, c = gid % C;
  int len = rowlen[row];
  size_t base = (size_t)row * CAP;
  const float* Hbase = H + (size_t)(row >> 11) * ((size_t)NN * C);
  float acc = 0.f;
  for (int n = 0; n < len; n += 4) {
    int c0 = ellc[base+n], c1 = ellc[base+n+1], c2 = ellc[base+n+2], c3 = ellc[base+n+3];
    float v0 = ellv[base+n], v1 = ellv[base+n+1], v2 = ellv[base+n+2], v3 = ellv[base+n+3];
    float h0 = Hbase[(size_t)c0*C+c], h1 = Hbase[(size_t)c1*C+c];
    float h2 = Hbase[(size_t)c2*C+c], h3 = Hbase[(size_t)c3*C+c];
    if (WEIGHTED) acc += v0*h0 + v1*h1 + v2*h2 + v3*h3;
    else acc += (v0>0.f?h0:0.f) + (v1>0.f?h1:0.f) + (v2>0.f?h2:0.f) + (v3>0.f?h3:0.f);
  }
  if (SELFLOOP) acc += H[(size_t)row*C + c];
  float z = SCALED ? scale[row]*acc : acc;
  out[(size_t)gid] = z;
}

// BN stats for one level: Zw [RTOT,30] + Zb [RTOT,CB]. 64 blocks, each owns
// bucket blockIdx (no atomics). Channel-aligned coalesced reads.
template<int CB>
__global__ __launch_bounds__(256) void k_stats(
    const float* __restrict__ Zw, const float* __restrict__ Zb,
    float* __restrict__ bkt)
{
  constexpr int CT = 30 + CB;
  __shared__ float red1[256], red2[256];
  int t = threadIdx.x;
  int r0 = blockIdx.x * 256;   // 256 rows per block (16384/64)
  // part A: C=30, 240 threads, 8 rows per iter, 32 iters
  {
    float s1 = 0.f, s2 = 0.f;
    if (t < 240) {
      int c = t % 30;  // rl = t / 30
      const float* p = Zw + (size_t)(r0 + t/30)*30 + c;
      for (int it = 0; it < 32; ++it) { float v = p[(size_t)it*240]; s1 += v; s2 += v*v; }
    }
    red1[t] = s1; red2[t] = s2;
    __syncthreads();
    if (t < 30) {
      float a = 0.f, b = 0.f;
      for (int g = 0; g < 8; ++g) { a += red1[g*30+t]; b += red2[g*30+t]; }
      bkt[((size_t)blockIdx.x*CT + t)*2]   = a;
      bkt[((size_t)blockIdx.x*CT + t)*2+1] = b;
    }
    __syncthreads();
  }
  // part B: C=CB
  if (CB == 30) {
    float s1 = 0.f, s2 = 0.f;
    if (t < 240) {
      int c = t % 30;
      const float* p = Zb + (size_t)(r0 + t/30)*30 + c;
      for (int it = 0; it < 32; ++it) { float v = p[(size_t)it*240]; s1 += v; s2 += v*v; }
    }
    red1[t] = s1; red2[t] = s2;
    __syncthreads();
    if (t < 30) {
      float a = 0.f, b = 0.f;
      for (int g = 0; g < 8; ++g) { a += red1[g*30+t]; b += red2[g*30+t]; }
      bkt[((size_t)blockIdx.x*CT + 30 + t)*2]   = a;
      bkt[((size_t)blockIdx.x*CT + 30 + t)*2+1] = b;
    }
  } else {
    float s1 = 0.f, s2 = 0.f;
    if (t < 200) {
      int c = t % 100;
      const float* p = Zb + (size_t)(r0 + t/100)*100 + c;
      for (int it = 0; it < 128; ++it) { float v = p[(size_t)it*200]; s1 += v; s2 += v*v; }
    }
    red1[t] = s1; red2[t] = s2;
    __syncthreads();
    if (t < 100) {
      float a = red1[t] + red1[100+t];
      float b = red2[t] + red2[100+t];
      bkt[((size_t)blockIdx.x*CT + 30 + t)*2]   = a;
      bkt[((size_t)blockIdx.x*CT + 30 + t)*2+1] = b;
    }
  }
}

// reduce stat buckets -> per-channel BN scale a and shift
__global__ void k_finalize(const float* __restrict__ bkt, int nbkt, int ctot,
    float count, const float* gA, const float* bA, int cA, float* outA,
    const float* gB, const float* bB, int cB, float* outB)
{
  int c = threadIdx.x;
  if (c >= ctot) return;
  float s1 = 0.f, s2 = 0.f;
  for (int b = 0; b < nbkt; ++b) {
    s1 += bkt[((size_t)b*ctot + c)*2];
    s2 += bkt[((size_t)b*ctot + c)*2 + 1];
  }
  float mean = s1 / count;
  float var  = s2 / count - mean*mean;
  float inv  = rsqrtf(var + 1e-5f);
  if (c < cA) { float a = gA[c]*inv; outA[c] = a; outA[cA + c] = bA[c] - mean*a; }
  else { int cc = c - cA; float a = gB[cc]*inv; outB[cc] = a; outB[cB + cc] = bB[cc] - mean*a; }
}

// apply BN -> store x/s -> next-layer weight GEMM, pre-scaled by dinv
__global__ __launch_bounds__(256) void k_apply_gemm(
    const float* __restrict__ Zw, const float* __restrict__ acW,
    float* __restrict__ xst, const float* __restrict__ Ww,
    float* __restrict__ Hwo, const float* __restrict__ dinvw,
    const float* __restrict__ Zb, const float* __restrict__ acB,
    float* __restrict__ sst, const float* __restrict__ Wb,
    float* __restrict__ Hbo, const float* __restrict__ dinvb, int coutb)
{
  int ct = 30 + coutb;
  int t = blockIdx.x * 256 + threadIdx.x;
  if (t >= RTOT * ct) return;
  int i = t / ct, c = t % ct;
  if (c < 30) {
    float xc = acW[c]*Zw[i*30+c] + acW[30+c];
    xst[i*30+c] = xc;
    float acc = 0.f;
    for (int k = 0; k < 30; ++k) {
      float xv = acW[k]*Zw[i*30+k] + acW[30+k];
      acc += xv * Ww[k*30+c];
    }
    Hwo[i*30+c] = dinvw[i]*acc;
  } else {
    int cc = c - 30;
    if (cc < 30) sst[i*30+cc] = acB[cc]*Zb[i*30+cc] + acB[30+cc];
    float acc = 0.f;
    for (int k = 0; k < 30; ++k) {
      float sv = acB[k]*Zb[i*30+k] + acB[30+k];
      acc += sv * Wb[k*coutb + cc];
    }
    Hbo[(size_t)i*coutb + cc] = dinvb[i]*acc;
  }
}

// BN(Z3w)->x13 store; s13=BN(Z3b); s1 = [s11|s12|s13] @ Wfc + bfc  (raw, softmax later)
__global__ __launch_bounds__(256) void k_fcpool(
    const float* __restrict__ Zw3, const float* __restrict__ acW3,
    const float* __restrict__ Zb3, const float* __restrict__ acB3,
    const float* __restrict__ s11, const float* __restrict__ s12,
    const float* __restrict__ Wfc, const float* __restrict__ bfc,
    float* __restrict__ x13, float* __restrict__ s1out)
{
  __shared__ float feat[64][160];
  __shared__ float Wl[40][100];
  int t = threadIdx.x;
  int g0 = blockIdx.x * 64;
  for (int idx = t; idx < 64*160; idx += 256) {
    int l = idx / 160, c = idx % 160;
    int g = g0 + l;
    float v;
    if (c < 30) v = s11[g*30 + c];
    else if (c < 60) v = s12[g*30 + (c-30)];
    else { int k = c - 60; v = acB3[k]*Zb3[(size_t)g*100 + k] + acB3[100 + k]; }
    feat[l][c] = v;
  }
  for (int idx = t; idx < 64*30; idx += 256) {
    int l = idx/30, c = idx%30;
    int g = g0 + l;
    x13[g*30+c] = acW3[c]*Zw3[g*30+c] + acW3[30+c];
  }
  int np = t >> 3, kg = t & 7;
  int n0 = np*2, n1 = np*2 + 1;
  int kbase = kg*12 + (kg < 4 ? kg : 4);
  int klen  = kg < 4 ? 13 : 12;
  float a0[13], a1[13];
#pragma unroll
  for (int j = 0; j < 13; ++j) { a0[j] = 0.f; a1[j] = 0.f; }
  for (int ch = 0; ch < 4; ++ch) {
    __syncthreads();
    for (int idx = t; idx < 4000; idx += 256) {
      int r = idx/100, j = idx%100;
      Wl[r][j] = Wfc[(ch*40 + r)*100 + j];
    }
    __syncthreads();
    for (int kk = 0; kk < 40; ++kk) {
      float f0 = feat[n0][ch*40+kk];
      float f1 = feat[n1][ch*40+kk];
#pragma unroll
      for (int j = 0; j < 13; ++j) {
        if (j < klen) {
          float w = Wl[kk][kbase + j];
          a0[j] += f0*w; a1[j] += f1*w;
        }
      }
    }
  }
  for (int j = 0; j < klen; ++j) {
    int k = kbase + j;
    s1out[(size_t)(g0+n0)*100 + k] = a0[j] + bfc[k];
    s1out[(size_t)(g0+n1)*100 + k] = a1[j] + bfc[k];
  }
}

// in-place softmax over 100 clusters, one wave per node
__global__ __launch_bounds__(256) void k_softmax(float* __restrict__ S)
{
  int w = threadIdx.x >> 6, lane = threadIdx.x & 63;
  int node = blockIdx.x * 4 + w;
  float* p = S + (size_t)node * 100;
  float v0 = p[lane];
  float v1 = lane < 36 ? p[64 + lane] : -3.4e38f;
  float m = fmaxf(v0, v1);
  for (int o = 32; o; o >>= 1) m = fmaxf(m, __shfl_xor(m, o));
  float e0 = expf(v0 - m);
  float e1 = lane < 36 ? expf(v1 - m) : 0.f;
  float s = e0 + e1;
  for (int o = 32; o; o >>= 1) s += __shfl_xor(s, o);
  float r = 1.f / s;
  p[lane] = e0 * r;
  if (lane < 36) p[64 + lane] = e1 * r;
}

// pooled partials: pp[blk][k][d] = sum over this block's 256 nodes of s[n,k]*feat[n,d]
// grid 64 = 8 batches * 8 chunks; NO atomics.
__global__ __launch_bounds__(256) void k_pool_part(
    const float* __restrict__ S, const float* __restrict__ x13,
    const float* __restrict__ As, float* __restrict__ pp)
{
  __shared__ float sL[64][100];
  __shared__ float xL[64][132];
  int t = threadIdx.x;
  int b = blockIdx.x >> 3, chunk = blockIdx.x & 7;
  int g00 = b * 2048 + chunk * 256;
  int kt = t/10, dt = t%10;
  int k0 = kt*4, d0 = dt*13;
  float acc[4][13];
#pragma unroll
  for (int a = 0; a < 4; ++a)
#pragma unroll
    for (int j = 0; j < 13; ++j) acc[a][j] = 0.f;
  for (int tile = 0; tile < 4; ++tile) {
    int g0 = g00 + tile*64;
    __syncthreads();
    for (int idx = t; idx < 64*100; idx += 256) {
      int l = idx/100, k = idx%100;
      sL[l][k] = S[(size_t)(g0+l)*100 + k];
    }
    for (int idx = t; idx < 64*130; idx += 256) {
      int l = idx/130, d = idx%130;
      xL[l][d] = d < 30 ? x13[(g0+l)*30 + d] : As[(size_t)(g0+l)*100 + (d-30)];
    }
    __syncthreads();
    if (t < 250) {
      for (int kk = 0; kk < 64; ++kk) {
        float sv[4];
#pragma unroll
        for (int a = 0; a < 4; ++a) sv[a] = sL[kk][k0+a];
#pragma unroll
        for (int j = 0; j < 13; ++j) {
          float xv = xL[kk][d0+j];
#pragma unroll
          for (int a = 0; a < 4; ++a) acc[a][j] += sv[a]*xv;
        }
      }
    }
  }
  if (t < 250) {
    float* dst = pp + (size_t)blockIdx.x * 13000;
    for (int a = 0; a < 4; ++a)
      for (int j = 0; j < 13; ++j)
        dst[(k0+a)*130 + (d0+j)] = acc[a][j];
  }
}

// reduce 8 chunk-partials per batch -> p1x, p1adj
__global__ __launch_bounds__(256) void k_pool_reduce(
    const float* __restrict__ pp, float* __restrict__ p1x, float* __restrict__ p1adj)
{
  int gid = blockIdx.x * 256 + threadIdx.x;
  if (gid >= BATCH*13000) return;
  int b = gid / 13000, rem = gid % 13000;
  float s = 0.f;
  for (int ch = 0; ch < 8; ++ch) s += pp[(size_t)(b*8 + ch)*13000 + rem];
  int k = rem / 130, d = rem % 130;
  if (d < 30) p1x[((size_t)b*100 + k)*30 + d] = s;
  else p1adj[((size_t)b*100 + k)*100 + (d-30)] = s;
}

// gcn-normalize pooled adjacency
__global__ __launch_bounds__(256) void k_norm_a2(const float* __restrict__ p1adj, float* __restrict__ A2)
{
  __shared__ float Ah[100*100];
  __shared__ float dl[100];
  int b = blockIdx.x, t = threadIdx.x;
  for (int idx = t; idx < 10000; idx += 256) {
    float v = p1adj[(size_t)b*10000 + idx];
    int i = idx/100, j = idx%100;
    if (i == j && v == 0.f) v = 1.f;  // add self-loop only where diag==0
    Ah[idx] = v;
  }
  __syncthreads();
  if (t < 100) {
    float s = 0.f;
    for (int j = 0; j < 100; ++j) s += Ah[t*100 + j];
    dl[t] = s > 0.f ? rsqrtf(s) : 0.f;
  }
  __syncthreads();
  for (int idx = t; idx < 10000; idx += 256) {
    int i = idx/100, j = idx%100;
    A2[(size_t)b*10000 + idx] = dl[i]*dl[j]*Ah[idx];
  }
}

// stage-2 GCN layer: (optional BN-apply of Zprev -> Xin, store) then Z = A2 @ (Xin @ W).
// BN stats via LDS reduce + plain write (one block per batch owns its bucket).
__global__ __launch_bounds__(256) void k_s2layer(
    const float* __restrict__ Xraw, const float* __restrict__ Zprev,
    const float* __restrict__ ac, float* __restrict__ xst,
    const float* __restrict__ Wm, const float* __restrict__ A2,
    float* __restrict__ Zout, float* __restrict__ bkt)
{
  __shared__ float Xl[100*30];
  __shared__ float Tl[100*30];
  __shared__ float Al[100*100];
  __shared__ float st1[30], st2[30];
  int b = blockIdx.x, t = threadIdx.x;
  if (t < 30) { st1[t] = 0.f; st2[t] = 0.f; }
  for (int idx = t; idx < 3000; idx += 256) {
    float v;
    if (ac == nullptr) v = Xraw[(size_t)b*3000 + idx];
    else {
      int c = idx % 30;
      v = ac[c]*Zprev[(size_t)b*3000 + idx] + ac[30+c];
      xst[(size_t)b*3000 + idx] = v;
    }
    Xl[idx] = v;
  }
  for (int idx = t; idx < 10000; idx += 256) Al[idx] = A2[(size_t)b*10000 + idx];
  __syncthreads();
  for (int idx = t; idx < 3000; idx += 256) {
    int i = idx/30, c = idx%30;
    float acc = 0.f;
    for (int k = 0; k < 30; ++k) acc += Xl[i*30+k]*Wm[k*30+c];
    Tl[idx] = acc;
  }
  __syncthreads();
  for (int idx = t; idx < 3000; idx += 256) {
    int i = idx/30, c = idx%30;
    float acc = 0.f;
    for (int j = 0; j < 100; ++j) acc += Al[i*100+j]*Tl[j*30+c];
    Zout[(size_t)b*3000 + idx] = acc;
    atomicAdd(&st1[c], acc);
    atomicAdd(&st2[c], acc*acc);
  }
  __syncthreads();
  if (t < 30) {
    bkt[((size_t)b*30 + t)*2]   = st1[t];
    bkt[((size_t)b*30 + t)*2+1] = st2[t];
  }
}

// stage-1 per-segment column max of [x11|x12|x13]
__global__ __launch_bounds__(128) void k_max1(
    const float* __restrict__ x11, const float* __restrict__ x12,
    const float* __restrict__ x13, float* __restrict__ pm)
{
  int b = blockIdx.x >> 3, seg = blockIdx.x & 7;
  int c = threadIdx.x;
  if (c >= 90) return;
  const float* src = c < 30 ? x11 : (c < 60 ? x12 : x13);
  int cc = c % 30;
  int r0 = b*2048 + seg*256;
  float m = -3.4e38f;
  for (int i = 0; i < 256; ++i) m = fmaxf(m, src[(size_t)(r0+i)*30 + cc]);
  pm[(size_t)(b*8+seg)*90 + c] = m;
}

// finish maxes: x1out from partials; x2out from x21/x22/BN(Z23)
__global__ __launch_bounds__(128) void k_max2(
    const float* __restrict__ pm, const float* __restrict__ x21,
    const float* __restrict__ x22, const float* __restrict__ Z23,
    const float* __restrict__ ac23, float* __restrict__ x1out, float* __restrict__ x2out)
{
  int b = blockIdx.x, c = threadIdx.x;
  if (c >= 90) return;
  float m = -3.4e38f;
  for (int s = 0; s < 8; ++s) m = fmaxf(m, pm[(size_t)(b*8+s)*90 + c]);
  x1out[b*90+c] = m;
  float m2 = -3.4e38f;
  int cc = c % 30;
  for (int i = 0; i < 100; ++i) {
    float v;
    if (c < 30) v = x21[(size_t)b*3000 + i*30 + cc];
    else if (c < 60) v = x22[(size_t)b*3000 + i*30 + cc];
    else v = ac23[cc]*Z23[(size_t)b*3000 + i*30 + cc] + ac23[30+cc];
    m2 = fmaxf(m2, v);
  }
  x2out[b*90+c] = m2;
}

__global__ __launch_bounds__(512) void k_mlp(
    const float* __restrict__ x1out, const float* __restrict__ x2out,
    const float* __restrict__ W1, const float* __restrict__ b1,
    const float* __restrict__ W2, const float* __restrict__ b2,
    float* __restrict__ out)
{
  __shared__ float hh[400];
  int t = threadIdx.x;
  if (t < 400) {
    int b = t/50, j = t%50;
    float acc = b1[j];
    for (int k = 0; k < 90; ++k) acc += x1out[b*90+k]*W1[k*50+j];
    for (int k = 0; k < 90; ++k) acc += x2out[b*90+k]*W1[(90+k)*50+j];
    hh[t] = fmaxf(acc, 0.f);
  }
  __syncthreads();
  if (t < 48) {
    int b = t/6, o = t%6;
    float acc = b2[o];
    for (int j = 0; j < 50; ++j) acc += hh[b*50+j]*W2[j*6+o];
    out[b*6+o] = acc;
  }
}

// ---------------- launcher ----------------
extern "C" void kernel_launch(void* const* d_in, const int* in_sizes, int n_in,
                              void* d_out, int out_size, void* d_ws, size_t ws_size,
                              hipStream_t stream)
{
  const float* x    = (const float*)d_in[0];
  const float* adj  = (const float*)d_in[1];
  const float* Win  = (const float*)d_in[2];
  const float* W3030= (const float*)d_in[3];
  const float* Wp13 = (const float*)d_in[4];
  // d_in[5]=b30, d_in[6]=b100: cancel through training-mode BN -> unused
  const float* Wfc  = (const float*)d_in[7];
  const float* bfc  = (const float*)d_in[8];
  const float* W1   = (const float*)d_in[9];
  const float* b1   = (const float*)d_in[10];
  const float* W2   = (const float*)d_in[11];
  const float* b2   = (const float*)d_in[12];
  const float* g30  = (const float*)d_in[13];
  const float* be30 = (const float*)d_in[14];
  const float* g100 = (const float*)d_in[15];
  const float* be100= (const float*)d_in[16];
  float* out = (float*)d_out;

  float* wsf = (float*)d_ws;
  float* bktL1 = wsf + OF_BKT_L1;
  float* bktL2 = wsf + OF_BKT_L2;
  float* bktL3 = wsf + OF_BKT_L3;
  float* bktS2a = wsf + OF_BKT_S2A;
  float* bktS2b = wsf + OF_BKT_S2B;
  float* bktS2c = wsf + OF_BKT_S2C;
  float* p1x   = wsf + OF_P1X;
  float* p1adj = wsf + OF_P1ADJ;
  float* ellv  = wsf + OF_ELLV;
  unsigned short* ellc = (unsigned short*)(wsf + OF_ELLC);
  int*   rowlen = (int*)(wsf + OF_ROWLEN);
  float* dinvw = wsf + OF_DINVW;
  float* dinvb = wsf + OF_DINVB;
  float* Hw = wsf + OF_HW;
  float* Hb = wsf + OF_HB;      // later: softmax S
  float* Zw = wsf + OF_ZW;
  float* Zb = wsf + OF_ZB;      // later: As = adj@s
  float* x11 = wsf + OF_X11;
  float* x12 = wsf + OF_X12;
  float* x13 = wsf + OF_X13;
  float* s11 = wsf + OF_S11;
  float* s12 = wsf + OF_S12;
  float* pp  = wsf + OF_S11;    // pool partials reuse s11+s12 (dead after fcpool)
  float* acw1 = wsf + OF_AC + 0;
  float* acb1 = wsf + OF_AC + 256;
  float* acw2 = wsf + OF_AC + 512;
  float* acb2 = wsf + OF_AC + 768;
  float* acw3 = wsf + OF_AC + 1024;
  float* acb3 = wsf + OF_AC + 1280;
  float* acs1 = wsf + OF_AC + 1536;
  float* acs2 = wsf + OF_AC + 1792;
  float* acs3 = wsf + OF_AC + 2048;
  float* A2  = wsf + OF_A2;
  float* Z21 = wsf + OF_Z21;
  float* Z22 = wsf + OF_Z22;
  float* Z23 = wsf + OF_Z23;
  float* x21 = wsf + OF_X21;
  float* x22 = wsf + OF_X22;
  float* partmax = wsf + OF_PARTMAX;
  float* x1out = wsf + OF_X1OUT;
  float* x2out = wsf + OF_X2OUT;

  k_build_ell<<<RTOT, 256, 0, stream>>>(adj, ellv, ellc, rowlen, dinvw, dinvb);
  k_h1<<<(RTOT*30)/256, 256, 0, stream>>>(x, Win, dinvw, dinvb, Hw, Hb);

  // level 1
  k_spmm<30,true ,true,true ><<<1920, 256, 0, stream>>>(Hw, ellv, ellc, rowlen, dinvw, Zw);
  k_spmm<30,false,true,true ><<<1920, 256, 0, stream>>>(Hb, ellv, ellc, rowlen, dinvb, Zb);
  k_stats<30><<<64, 256, 0, stream>>>(Zw, Zb, bktL1);
  k_finalize<<<1, 256, 0, stream>>>(bktL1, 64, 60, 16384.f, g30+0,  be30+0,  30, acw1, g30+90,  be30+90,  30, acb1);
  k_apply_gemm<<<(RTOT*60)/256, 256, 0, stream>>>(Zw, acw1, x11, W3030+0,   Hw, dinvw, Zb, acb1, s11, W3030+2*900, Hb, dinvb, 30);

  // level 2
  k_spmm<30,true ,true,true ><<<1920, 256, 0, stream>>>(Hw, ellv, ellc, rowlen, dinvw, Zw);
  k_spmm<30,false,true,true ><<<1920, 256, 0, stream>>>(Hb, ellv, ellc, rowlen, dinvb, Zb);
  k_stats<30><<<64, 256, 0, stream>>>(Zw, Zb, bktL2);
  k_finalize<<<1, 256, 0, stream>>>(bktL2, 64, 60, 16384.f, g30+30, be30+30, 30, acw2, g30+120, be30+120, 30, acb2);
  k_apply_gemm<<<(RTOT*130)/256, 256, 0, stream>>>(Zw, acw2, x12, W3030+900, Hw, dinvw, Zb, acb2, s12, Wp13,        Hb, dinvb, 100);

  // level 3
  k_spmm<30,true ,true,true ><<<1920, 256, 0, stream>>>(Hw, ellv, ellc, rowlen, dinvw, Zw);
  k_spmm<100,false,true,true><<<6400, 256, 0, stream>>>(Hb, ellv, ellc, rowlen, dinvb, Zb);
  k_stats<100><<<64, 256, 0, stream>>>(Zw, Zb, bktL3);
  k_finalize<<<1, 256, 0, stream>>>(bktL3, 64, 130, 16384.f, g30+60, be30+60, 30, acw3, g100, be100, 100, acb3);

  // pooling assignment
  k_fcpool<<<256, 256, 0, stream>>>(Zw, acw3, Zb, acb3, s11, s12, Wfc, bfc, x13, Hb /* S */);
  k_softmax<<<4096, 256, 0, stream>>>(Hb);
  k_spmm<100,true,false,false><<<6400, 256, 0, stream>>>(Hb, ellv, ellc, rowlen, nullptr, Zb /* As */);
  k_pool_part<<<64, 256, 0, stream>>>(Hb, x13, Zb, pp);
  k_pool_reduce<<<(BATCH*13000 + 255)/256, 256, 0, stream>>>(pp, p1x, p1adj);
  k_norm_a2<<<BATCH, 256, 0, stream>>>(p1adj, A2);

  // stage 2
  k_s2layer<<<BATCH, 256, 0, stream>>>(p1x, nullptr, nullptr, nullptr, W3030+3*900, A2, Z21, bktS2a);
  k_finalize<<<1, 256, 0, stream>>>(bktS2a, 8, 30, 800.f, g30+150, be30+150, 30, acs1, nullptr, nullptr, 0, nullptr);
  k_s2layer<<<BATCH, 256, 0, stream>>>(nullptr, Z21, acs1, x21, W3030+4*900, A2, Z22, bktS2b);
  k_finalize<<<1, 256, 0, stream>>>(bktS2b, 8, 30, 800.f, g30+180, be30+180, 30, acs2, nullptr, nullptr, 0, nullptr);
  k_s2layer<<<BATCH, 256, 0, stream>>>(nullptr, Z22, acs2, x22, W3030+5*900, A2, Z23, bktS2c);
  k_finalize<<<1, 256, 0, stream>>>(bktS2c, 8, 30, 800.f, g30+210, be30+210, 30, acs3, nullptr, nullptr, 0, nullptr);

  // readout
  k_max1<<<64, 128, 0, stream>>>(x11, x12, x13, partmax);
  k_max2<<<BATCH, 128, 0, stream>>>(partmax, x21, x22, Z23, acs3, x1out, x2out);
  k_mlp<<<1, 512, 0, stream>>>(x1out, x2out, W1, b1, W2, b2, out);
}

// Round 3
// 839.292 us; speedup vs baseline: 1.4392x; 1.1645x over previous
//
#include <hip/hip_runtime.h>
#include <cstdint>
#include <cstddef>

#define BATCH 8
#define NN 2048
#define RTOT 16384   // BATCH*NN
#define KCL 100
#define CAP 176      // ELL row capacity (mean nnz/row ~102, sigma ~10; 7.5 sigma headroom)

// ---------------- workspace layout (offsets in floats) ----------------
static constexpr size_t OF_BKT_L1 = 0;            // 64*60*2
static constexpr size_t OF_BKT_L2 = 7680;
static constexpr size_t OF_BKT_L3 = 15360;        // 64*130*2
static constexpr size_t OF_BKT_S2A = 32000;
static constexpr size_t OF_BKT_S2B = 32480;
static constexpr size_t OF_BKT_S2C = 32960;
static constexpr size_t OF_P1X    = 33440;        // 8*100*30
static constexpr size_t OF_P1ADJ  = 57440;        // 8*100*100
static constexpr size_t OF_AC     = 137440;       // 9 slots * 256
static constexpr size_t OF_ELLV   = 139744;                   // 16384*176
static constexpr size_t OF_ELLC   = OF_ELLV + 2883584;        // u16 x 16384*176 = 1441792 floats
static constexpr size_t OF_ROWLEN = OF_ELLC + 1441792;
static constexpr size_t OF_DINVW  = OF_ROWLEN + 16384;
static constexpr size_t OF_DINVB  = OF_DINVW + 16384;
static constexpr size_t OF_HW     = OF_DINVB + 16384;         // 16384*32 (stride 32, pad 0)
static constexpr size_t OF_HB     = OF_HW + 524288;           // 16384*100 max (stride 32 or 100; reused as S)
static constexpr size_t OF_ZW     = OF_HB + 1638400;          // 16384*32
static constexpr size_t OF_ZB     = OF_ZW + 524288;           // 16384*100 max (reused as As)
static constexpr size_t OF_X11    = OF_ZB + 1638400;          // stride 32
static constexpr size_t OF_X12    = OF_X11 + 524288;
static constexpr size_t OF_X13    = OF_X12 + 524288;
static constexpr size_t OF_S11    = OF_X13 + 524288;          // stride 32; s11+s12 reused as pool partials
static constexpr size_t OF_S12    = OF_S11 + 524288;
static constexpr size_t OF_A2     = OF_S12 + 524288;          // 8*100*100
static constexpr size_t OF_Z21    = OF_A2 + 80000;            // stage-2 stride 30
static constexpr size_t OF_Z22    = OF_Z21 + 24000;
static constexpr size_t OF_Z23    = OF_Z22 + 24000;
static constexpr size_t OF_X21    = OF_Z23 + 24000;
static constexpr size_t OF_X22    = OF_X21 + 24000;
static constexpr size_t OF_PARTMAX= OF_X22 + 24000;           // 8*8*90
static constexpr size_t OF_X1OUT  = OF_PARTMAX + 5760;
static constexpr size_t OF_X2OUT  = OF_X1OUT + 720;

#define FMA4(acc, s, h) { acc.x += (s)*(h).x; acc.y += (s)*(h).y; acc.z += (s)*(h).z; acc.w += (s)*(h).w; }

// ---------------- kernels ----------------

// One pass over adj: build ELL (val fp32 + col u16), weighted degree, binary degree.
__global__ __launch_bounds__(256) void k_build_ell(
    const float* __restrict__ adj, float* __restrict__ ellv,
    unsigned short* __restrict__ ellc, int* __restrict__ rowlen,
    float* __restrict__ dinvw, float* __restrict__ dinvb)
{
  int r = blockIdx.x;
  const float* row = adj + (size_t)r * NN;
  __shared__ int cnt;
  __shared__ float wsum[4];
  int t = threadIdx.x, lane = t & 63;
  if (t == 0) cnt = 0;
  __syncthreads();
  float sum = 0.f;
  size_t base = (size_t)r * CAP;
  for (int h = 0; h < 2; ++h) {
    int col0 = h * 1024 + t * 4;
    float4 v4 = *(const float4*)(row + col0);
    float vv[4] = {v4.x, v4.y, v4.z, v4.w};
#pragma unroll
    for (int k = 0; k < 4; ++k) {
      float v = vv[k];
      sum += v;
      bool p = (v != 0.f);
      unsigned long long m = __ballot(p);
      int c_ = __popcll(m);
      int bw = 0;
      if (lane == 0) bw = atomicAdd(&cnt, c_);
      bw = __shfl(bw, 0);
      if (p) {
        int pos = bw + __popcll(m & ((1ull << lane) - 1ull));
        if (pos < CAP) { ellv[base + pos] = v; ellc[base + pos] = (unsigned short)(col0 + k); }
      }
    }
  }
  for (int o = 32; o > 0; o >>= 1) sum += __shfl_down(sum, o);
  if (lane == 0) wsum[t >> 6] = sum;
  __syncthreads();
  if (t == 0) {
    float tot = wsum[0] + wsum[1] + wsum[2] + wsum[3];
    int n = cnt; if (n > CAP) n = CAP;
    int nnz = n;
    while ((n & 3) && n < CAP) { ellv[base + n] = 0.f; ellc[base + n] = 0; ++n; }
    rowlen[r] = n;
    dinvw[r] = rsqrtf(tot + 1.f);
    dinvb[r] = rsqrtf((float)nnz + 1.f);
  }
}

// H1 = x @ W_in[0/1], pre-scaled by dinv; stride-32 output with zero pad
__global__ __launch_bounds__(256) void k_h1(
    const float* __restrict__ x, const float* __restrict__ Win,
    const float* __restrict__ dinvw, const float* __restrict__ dinvb,
    float* __restrict__ Hw, float* __restrict__ Hb)
{
  int gid = blockIdx.x * 256 + threadIdx.x;   // RTOT*32
  int i = gid >> 5, c = gid & 31;
  float hw = 0.f, hb = 0.f;
  if (c < 30) {
    float x0 = x[i*3], x1 = x[i*3+1], x2 = x[i*3+2];
    hw = (x0*Win[c]    + x1*Win[30+c]  + x2*Win[60+c])  * dinvw[i];
    hb = (x0*Win[90+c] + x1*Win[120+c] + x2*Win[150+c]) * dinvb[i];
  }
  Hw[gid] = hw;
  Hb[gid] = hb;
}

// Fused ELL SpMM pair (stride-32 channels, float4 per thread):
// Zw = dinvw * (Aw-gather(Hw) + Hw_self), Zb = dinvb * (binary-gather(Hb) + Hb_self)
template<bool PAIR>
__global__ __launch_bounds__(256) void k_spmm32(
    const float* __restrict__ Hw, const float* __restrict__ Hb,
    const float* __restrict__ ellv, const unsigned short* __restrict__ ellc,
    const int* __restrict__ rowlen, const float* __restrict__ dinvw,
    const float* __restrict__ dinvb, float* __restrict__ Zw, float* __restrict__ Zb)
{
  int gid = blockIdx.x * 256 + threadIdx.x;   // RTOT*8
  int row = gid >> 3, q = gid & 7;
  int len = rowlen[row];
  const float4* ev = (const float4*)(ellv + (size_t)row * CAP);
  const uint2*  ec = (const uint2*) (ellc + (size_t)row * CAP);
  const float4* HW4 = (const float4*)Hw + (size_t)(row >> 11) * (NN*8);
  const float4* HB4 = (const float4*)Hb + (size_t)(row >> 11) * (NN*8);
  float4 aw = {0,0,0,0}, ab = {0,0,0,0};
  int nit = len >> 2;
  for (int i = 0; i < nit; ++i) {
    float4 v = ev[i];
    uint2 cc = ec[i];
    int c0 = cc.x & 0xffff, c1 = cc.x >> 16, c2 = cc.y & 0xffff, c3 = cc.y >> 16;
    float4 h0 = HW4[c0*8+q], h1 = HW4[c1*8+q], h2 = HW4[c2*8+q], h3 = HW4[c3*8+q];
    FMA4(aw, v.x, h0); FMA4(aw, v.y, h1); FMA4(aw, v.z, h2); FMA4(aw, v.w, h3);
    if (PAIR) {
      float4 g0 = HB4[c0*8+q], g1 = HB4[c1*8+q], g2 = HB4[c2*8+q], g3 = HB4[c3*8+q];
      float b0 = v.x>0.f?1.f:0.f, b1 = v.y>0.f?1.f:0.f, b2 = v.z>0.f?1.f:0.f, b3 = v.w>0.f?1.f:0.f;
      FMA4(ab, b0, g0); FMA4(ab, b1, g1); FMA4(ab, b2, g2); FMA4(ab, b3, g3);
    }
  }
  int rl = (row & (NN-1));
  float4 hs = HW4[rl*8+q];
  aw.x += hs.x; aw.y += hs.y; aw.z += hs.z; aw.w += hs.w;
  float dw = dinvw[row];
  float4 ow = {dw*aw.x, dw*aw.y, dw*aw.z, dw*aw.w};
  ((float4*)Zw)[(size_t)row*8+q] = ow;
  if (PAIR) {
    float4 gs = HB4[rl*8+q];
    ab.x += gs.x; ab.y += gs.y; ab.z += gs.z; ab.w += gs.w;
    float db = dinvb[row];
    float4 ob = {db*ab.x, db*ab.y, db*ab.z, db*ab.w};
    ((float4*)Zb)[(size_t)row*8+q] = ob;
  }
}

// ELL SpMM, C=100 (stride 100 = 25 float4/row)
template<bool WEIGHTED, bool SELFLOOP, bool SCALED>
__global__ __launch_bounds__(256) void k_spmm100(
    const float* __restrict__ H, const float* __restrict__ ellv,
    const unsigned short* __restrict__ ellc, const int* __restrict__ rowlen,
    const float* __restrict__ scale, float* __restrict__ Z)
{
  int gid = blockIdx.x * 256 + threadIdx.x;   // RTOT*25
  int row = gid / 25, q = gid - row*25;
  int len = rowlen[row];
  const float4* ev = (const float4*)(ellv + (size_t)row * CAP);
  const uint2*  ec = (const uint2*) (ellc + (size_t)row * CAP);
  const float4* H4 = (const float4*)H + (size_t)(row >> 11) * (NN*25);
  float4 acc = {0,0,0,0};
  int nit = len >> 2;
  for (int i = 0; i < nit; ++i) {
    float4 v = ev[i];
    uint2 cc = ec[i];
    int c0 = cc.x & 0xffff, c1 = cc.x >> 16, c2 = cc.y & 0xffff, c3 = cc.y >> 16;
    float4 h0 = H4[c0*25+q], h1 = H4[c1*25+q], h2 = H4[c2*25+q], h3 = H4[c3*25+q];
    float w0 = WEIGHTED ? v.x : (v.x>0.f?1.f:0.f);
    float w1 = WEIGHTED ? v.y : (v.y>0.f?1.f:0.f);
    float w2 = WEIGHTED ? v.z : (v.z>0.f?1.f:0.f);
    float w3 = WEIGHTED ? v.w : (v.w>0.f?1.f:0.f);
    FMA4(acc, w0, h0); FMA4(acc, w1, h1); FMA4(acc, w2, h2); FMA4(acc, w3, h3);
  }
  if (SELFLOOP) {
    float4 hs = H4[(row & (NN-1))*25+q];
    acc.x += hs.x; acc.y += hs.y; acc.z += hs.z; acc.w += hs.w;
  }
  float s = SCALED ? scale[row] : 1.f;
  float4 o = {s*acc.x, s*acc.y, s*acc.z, s*acc.w};
  ((float4*)Z)[(size_t)row*25+q] = o;
}

// BN stats, both Z arrays stride 32. bkt layout: [(blk*CT + ch)*2 + {0,1}]
__global__ __launch_bounds__(256) void k_stats32(
    const float* __restrict__ Zw, const float* __restrict__ Zb,
    float* __restrict__ bkt, int CT)
{
  __shared__ float r1[256], r2[256];
  int t = threadIdx.x, c = t & 31, rg = t >> 5;
  int r0 = blockIdx.x * 256;
  {
    const float* p = Zw + (size_t)(r0+rg)*32 + c;
    float s1 = 0.f, s2 = 0.f;
    for (int it = 0; it < 32; ++it) { float v = p[it*256]; s1 += v; s2 += v*v; }
    r1[t] = s1; r2[t] = s2;
    __syncthreads();
    if (t < 30) {
      float a = 0.f, b = 0.f;
      for (int g = 0; g < 8; ++g) { a += r1[g*32+t]; b += r2[g*32+t]; }
      bkt[((size_t)blockIdx.x*CT + t)*2]   = a;
      bkt[((size_t)blockIdx.x*CT + t)*2+1] = b;
    }
    __syncthreads();
  }
  {
    const float* p = Zb + (size_t)(r0+rg)*32 + c;
    float s1 = 0.f, s2 = 0.f;
    for (int it = 0; it < 32; ++it) { float v = p[it*256]; s1 += v; s2 += v*v; }
    r1[t] = s1; r2[t] = s2;
    __syncthreads();
    if (t < 30) {
      float a = 0.f, b = 0.f;
      for (int g = 0; g < 8; ++g) { a += r1[g*32+t]; b += r2[g*32+t]; }
      bkt[((size_t)blockIdx.x*CT + 30 + t)*2]   = a;
      bkt[((size_t)blockIdx.x*CT + 30 + t)*2+1] = b;
    }
  }
}

// BN stats level 3: Zw stride 32 (ch 0..29), Zb stride 100 (ch 30..129); CT=130
__global__ __launch_bounds__(256) void k_stats_l3(
    const float* __restrict__ Zw, const float* __restrict__ Zb,
    float* __restrict__ bkt)
{
  __shared__ float r1[256], r2[256];
  int t = threadIdx.x, c = t & 31, rg = t >> 5;
  int r0 = blockIdx.x * 256;
  {
    const float* p = Zw + (size_t)(r0+rg)*32 + c;
    float s1 = 0.f, s2 = 0.f;
    for (int it = 0; it < 32; ++it) { float v = p[it*256]; s1 += v; s2 += v*v; }
    r1[t] = s1; r2[t] = s2;
    __syncthreads();
    if (t < 30) {
      float a = 0.f, b = 0.f;
      for (int g = 0; g < 8; ++g) { a += r1[g*32+t]; b += r2[g*32+t]; }
      bkt[((size_t)blockIdx.x*130 + t)*2]   = a;
      bkt[((size_t)blockIdx.x*130 + t)*2+1] = b;
    }
    __syncthreads();
  }
  {
    float s1 = 0.f, s2 = 0.f;
    if (t < 200) {
      int ch = t % 100;
      const float* p = Zb + (size_t)(r0 + t/100)*100 + ch;
      for (int it = 0; it < 128; ++it) { float v = p[(size_t)it*200]; s1 += v; s2 += v*v; }
    }
    r1[t] = s1; r2[t] = s2;
    __syncthreads();
    if (t < 100) {
      float a = r1[t] + r1[100+t];
      float b = r2[t] + r2[100+t];
      bkt[((size_t)blockIdx.x*130 + 30 + t)*2]   = a;
      bkt[((size_t)blockIdx.x*130 + 30 + t)*2+1] = b;
    }
  }
}

// reduce stat buckets -> per-channel BN scale a and shift
__global__ void k_finalize(const float* __restrict__ bkt, int nbkt, int ctot,
    float count, const float* gA, const float* bA, int cA, float* outA,
    const float* gB, const float* bB, int cB, float* outB)
{
  int c = threadIdx.x;
  if (c >= ctot) return;
  float s1 = 0.f, s2 = 0.f;
  for (int b = 0; b < nbkt; ++b) {
    s1 += bkt[((size_t)b*ctot + c)*2];
    s2 += bkt[((size_t)b*ctot + c)*2 + 1];
  }
  float mean = s1 / count;
  float var  = s2 / count - mean*mean;
  float inv  = rsqrtf(var + 1e-5f);
  if (c < cA) { float a = gA[c]*inv; outA[c] = a; outA[cA + c] = bA[c] - mean*a; }
  else { int cc = c - cA; float a = gB[cc]*inv; outB[cc] = a; outB[cB + cc] = bB[cc] - mean*a; }
}

// apply BN -> store x/s (stride 32) -> next-layer weight GEMM pre-scaled by dinv.
// NGB groups of 4 output channels on b-side; OSTRIDEB = b-side out row stride (floats).
template<int NGB, int OSTRIDEB>
__global__ __launch_bounds__(256) void k_apply_gemm(
    const float* __restrict__ Zw, const float* __restrict__ acW,
    float* __restrict__ xst, const float* __restrict__ Ww,
    float* __restrict__ Hwo, const float* __restrict__ dinvw,
    const float* __restrict__ Zb, const float* __restrict__ acB,
    float* __restrict__ sst, const float* __restrict__ Wb,
    float* __restrict__ Hbo, const float* __restrict__ dinvb)
{
  constexpr int NG = 8 + NGB;
  __shared__ float WwL[30*32];
  __shared__ float WbL[30*OSTRIDEB];
  __shared__ float awL[60], abL[60];
  int t = threadIdx.x;
  for (int idx = t; idx < 30*32; idx += 256) {
    int k = idx >> 5, c = idx & 31;
    WwL[idx] = (c < 30) ? Ww[k*30 + c] : 0.f;
  }
  if (OSTRIDEB == 32) {
    for (int idx = t; idx < 30*32; idx += 256) {
      int k = idx >> 5, c = idx & 31;
      WbL[idx] = (c < 30) ? Wb[k*30 + c] : 0.f;
    }
  } else {
    for (int idx = t; idx < 30*OSTRIDEB; idx += 256) WbL[idx] = Wb[idx];
  }
  if (t < 60) { awL[t] = acW[t]; abL[t] = acB[t]; }
  __syncthreads();
  int gid = blockIdx.x * 256 + t;
  int row = gid / NG, g = gid % NG;
  if (g < 8) {
    const float4* Z4 = (const float4*)Zw + (size_t)row*8;
    float4 z4[8];
#pragma unroll
    for (int u = 0; u < 8; ++u) z4[u] = Z4[u];
    const float* z = (const float*)z4;
    float4 xv;
    {
      int ch = 4*g;
      xv.x = (ch+0 < 30) ? awL[ch+0]*z[ch+0] + awL[30+ch+0] : 0.f;
      xv.y = (ch+1 < 30) ? awL[ch+1]*z[ch+1] + awL[30+ch+1] : 0.f;
      xv.z = (ch+2 < 30) ? awL[ch+2]*z[ch+2] + awL[30+ch+2] : 0.f;
      xv.w = (ch+3 < 30) ? awL[ch+3]*z[ch+3] + awL[30+ch+3] : 0.f;
    }
    ((float4*)xst)[(size_t)row*8+g] = xv;
    float4 o = {0,0,0,0};
#pragma unroll
    for (int k = 0; k < 30; ++k) {
      float xk = awL[k]*z[k] + awL[30+k];
      float4 w = *(const float4*)(WwL + k*32 + 4*g);
      FMA4(o, xk, w);
    }
    float d = dinvw[row];
    float4 ov = {d*o.x, d*o.y, d*o.z, d*o.w};
    ((float4*)Hwo)[(size_t)row*8+g] = ov;
  } else {
    int gb = g - 8;
    const float4* Z4 = (const float4*)Zb + (size_t)row*8;
    float4 z4[8];
#pragma unroll
    for (int u = 0; u < 8; ++u) z4[u] = Z4[u];
    const float* z = (const float*)z4;
    if (gb < 8) {
      int ch = 4*gb;
      float4 sv;
      sv.x = (ch+0 < 30) ? abL[ch+0]*z[ch+0] + abL[30+ch+0] : 0.f;
      sv.y = (ch+1 < 30) ? abL[ch+1]*z[ch+1] + abL[30+ch+1] : 0.f;
      sv.z = (ch+2 < 30) ? abL[ch+2]*z[ch+2] + abL[30+ch+2] : 0.f;
      sv.w = (ch+3 < 30) ? abL[ch+3]*z[ch+3] + abL[30+ch+3] : 0.f;
      ((float4*)sst)[(size_t)row*8+gb] = sv;
    }
    float4 o = {0,0,0,0};
#pragma unroll
    for (int k = 0; k < 30; ++k) {
      float sk = abL[k]*z[k] + abL[30+k];
      float4 w = *(const float4*)(WbL + k*OSTRIDEB + 4*gb);
      FMA4(o, sk, w);
    }
    float d = dinvb[row];
    float4 ov = {d*o.x, d*o.y, d*o.z, d*o.w};
    ((float4*)Hbo)[(size_t)row*(OSTRIDEB/4) + gb] = ov;
  }
}

// BN(Z3w)->x13 (stride 32); s13=BN(Z3b); s1 = [s11|s12|s13] @ Wfc + bfc
__global__ __launch_bounds__(256) void k_fcpool(
    const float* __restrict__ Zw3, const float* __restrict__ acW3,
    const float* __restrict__ Zb3, const float* __restrict__ acB3,
    const float* __restrict__ s11, const float* __restrict__ s12,
    const float* __restrict__ Wfc, const float* __restrict__ bfc,
    float* __restrict__ x13, float* __restrict__ s1out)
{
  __shared__ float feat[64][160];
  __shared__ float Wl[40][100];
  int t = threadIdx.x;
  int g0 = blockIdx.x * 64;
  for (int idx = t; idx < 64*160; idx += 256) {
    int l = idx / 160, c = idx % 160;
    int g = g0 + l;
    float v;
    if (c < 30) v = s11[(size_t)g*32 + c];
    else if (c < 60) v = s12[(size_t)g*32 + (c-30)];
    else { int k = c - 60; v = acB3[k]*Zb3[(size_t)g*100 + k] + acB3[100 + k]; }
    feat[l][c] = v;
  }
  for (int idx = t; idx < 64*32; idx += 256) {
    int l = idx >> 5, c = idx & 31;
    int g = g0 + l;
    x13[(size_t)g*32+c] = (c < 30) ? acW3[c]*Zw3[(size_t)g*32+c] + acW3[30+c] : 0.f;
  }
  int np = t >> 3, kg = t & 7;
  int n0 = np*2, n1 = np*2 + 1;
  int kbase = kg*12 + (kg < 4 ? kg : 4);
  int klen  = kg < 4 ? 13 : 12;
  float a0[13], a1[13];
#pragma unroll
  for (int j = 0; j < 13; ++j) { a0[j] = 0.f; a1[j] = 0.f; }
  for (int ch = 0; ch < 4; ++ch) {
    __syncthreads();
    for (int idx = t; idx < 4000; idx += 256) {
      int r = idx/100, j = idx%100;
      Wl[r][j] = Wfc[(ch*40 + r)*100 + j];
    }
    __syncthreads();
    for (int kk = 0; kk < 40; ++kk) {
      float f0 = feat[n0][ch*40+kk];
      float f1 = feat[n1][ch*40+kk];
#pragma unroll
      for (int j = 0; j < 13; ++j) {
        if (j < klen) {
          float w = Wl[kk][kbase + j];
          a0[j] += f0*w; a1[j] += f1*w;
        }
      }
    }
  }
  for (int j = 0; j < klen; ++j) {
    int k = kbase + j;
    s1out[(size_t)(g0+n0)*100 + k] = a0[j] + bfc[k];
    s1out[(size_t)(g0+n1)*100 + k] = a1[j] + bfc[k];
  }
}

// in-place softmax over 100 clusters, one wave per node
__global__ __launch_bounds__(256) void k_softmax(float* __restrict__ S)
{
  int w = threadIdx.x >> 6, lane = threadIdx.x & 63;
  int node = blockIdx.x * 4 + w;
  float* p = S + (size_t)node * 100;
  float v0 = p[lane];
  float v1 = lane < 36 ? p[64 + lane] : -3.4e38f;
  float m = fmaxf(v0, v1);
  for (int o = 32; o; o >>= 1) m = fmaxf(m, __shfl_xor(m, o));
  float e0 = expf(v0 - m);
  float e1 = lane < 36 ? expf(v1 - m) : 0.f;
  float s = e0 + e1;
  for (int o = 32; o; o >>= 1) s += __shfl_xor(s, o);
  float r = 1.f / s;
  p[lane] = e0 * r;
  if (lane < 36) p[64 + lane] = e1 * r;
}

// pooled partials: pp[blk][k][d] over this block's 256 nodes; NO atomics
__global__ __launch_bounds__(256) void k_pool_part(
    const float* __restrict__ S, const float* __restrict__ x13,
    const float* __restrict__ As, float* __restrict__ pp)
{
  __shared__ float sL[64][100];
  __shared__ float xL[64][132];
  int t = threadIdx.x;
  int b = blockIdx.x >> 3, chunk = blockIdx.x & 7;
  int g00 = b * 2048 + chunk * 256;
  int kt = t/10, dt = t%10;
  int k0 = kt*4, d0 = dt*13;
  float acc[4][13];
#pragma unroll
  for (int a = 0; a < 4; ++a)
#pragma unroll
    for (int j = 0; j < 13; ++j) acc[a][j] = 0.f;
  for (int tile = 0; tile < 4; ++tile) {
    int g0 = g00 + tile*64;
    __syncthreads();
    for (int idx = t; idx < 64*100; idx += 256) {
      int l = idx/100, k = idx%100;
      sL[l][k] = S[(size_t)(g0+l)*100 + k];
    }
    for (int idx = t; idx < 64*130; idx += 256) {
      int l = idx/130, d = idx%130;
      xL[l][d] = d < 30 ? x13[(size_t)(g0+l)*32 + d] : As[(size_t)(g0+l)*100 + (d-30)];
    }
    __syncthreads();
    if (t < 250) {
      for (int kk = 0; kk < 64; ++kk) {
        float sv[4];
#pragma unroll
        for (int a = 0; a < 4; ++a) sv[a] = sL[kk][k0+a];
#pragma unroll
        for (int j = 0; j < 13; ++j) {
          float xv = xL[kk][d0+j];
#pragma unroll
          for (int a = 0; a < 4; ++a) acc[a][j] += sv[a]*xv;
        }
      }
    }
  }
  if (t < 250) {
    float* dst = pp + (size_t)blockIdx.x * 13000;
    for (int a = 0; a < 4; ++a)
      for (int j = 0; j < 13; ++j)
        dst[(k0+a)*130 + (d0+j)] = acc[a][j];
  }
}

// reduce 8 chunk-partials per batch -> p1x, p1adj
__global__ __launch_bounds__(256) void k_pool_reduce(
    const float* __restrict__ pp, float* __restrict__ p1x, float* __restrict__ p1adj)
{
  int gid = blockIdx.x * 256 + threadIdx.x;
  if (gid >= BATCH*13000) return;
  int b = gid / 13000, rem = gid % 13000;
  float s = 0.f;
  for (int ch = 0; ch < 8; ++ch) s += pp[(size_t)(b*8 + ch)*13000 + rem];
  int k = rem / 130, d = rem % 130;
  if (d < 30) p1x[((size_t)b*100 + k)*30 + d] = s;
  else p1adj[((size_t)b*100 + k)*100 + (d-30)] = s;
}

// gcn-normalize pooled adjacency
__global__ __launch_bounds__(256) void k_norm_a2(const float* __restrict__ p1adj, float* __restrict__ A2)
{
  __shared__ float Ah[100*100];
  __shared__ float dl[100];
  int b = blockIdx.x, t = threadIdx.x;
  for (int idx = t; idx < 10000; idx += 256) {
    float v = p1adj[(size_t)b*10000 + idx];
    int i = idx/100, j = idx%100;
    if (i == j && v == 0.f) v = 1.f;
    Ah[idx] = v;
  }
  __syncthreads();
  if (t < 100) {
    float s = 0.f;
    for (int j = 0; j < 100; ++j) s += Ah[t*100 + j];
    dl[t] = s > 0.f ? rsqrtf(s) : 0.f;
  }
  __syncthreads();
  for (int idx = t; idx < 10000; idx += 256) {
    int i = idx/100, j = idx%100;
    A2[(size_t)b*10000 + idx] = dl[i]*dl[j]*Ah[idx];
  }
}

// stage-2 GCN layer (stride 30), LDS-atomic BN stats, plain bucket write
__global__ __launch_bounds__(256) void k_s2layer(
    const float* __restrict__ Xraw, const float* __restrict__ Zprev,
    const float* __restrict__ ac, float* __restrict__ xst,
    const float* __restrict__ Wm, const float* __restrict__ A2,
    float* __restrict__ Zout, float* __restrict__ bkt)
{
  __shared__ float Xl[100*30];
  __shared__ float Tl[100*30];
  __shared__ float Al[100*100];
  __shared__ float st1[30], st2[30];
  int b = blockIdx.x, t = threadIdx.x;
  if (t < 30) { st1[t] = 0.f; st2[t] = 0.f; }
  for (int idx = t; idx < 3000; idx += 256) {
    float v;
    if (ac == nullptr) v = Xraw[(size_t)b*3000 + idx];
    else {
      int c = idx % 30;
      v = ac[c]*Zprev[(size_t)b*3000 + idx] + ac[30+c];
      xst[(size_t)b*3000 + idx] = v;
    }
    Xl[idx] = v;
  }
  for (int idx = t; idx < 10000; idx += 256) Al[idx] = A2[(size_t)b*10000 + idx];
  __syncthreads();
  for (int idx = t; idx < 3000; idx += 256) {
    int i = idx/30, c = idx%30;
    float acc = 0.f;
    for (int k = 0; k < 30; ++k) acc += Xl[i*30+k]*Wm[k*30+c];
    Tl[idx] = acc;
  }
  __syncthreads();
  for (int idx = t; idx < 3000; idx += 256) {
    int i = idx/30, c = idx%30;
    float acc = 0.f;
    for (int j = 0; j < 100; ++j) acc += Al[i*100+j]*Tl[j*30+c];
    Zout[(size_t)b*3000 + idx] = acc;
    atomicAdd(&st1[c], acc);
    atomicAdd(&st2[c], acc*acc);
  }
  __syncthreads();
  if (t < 30) {
    bkt[((size_t)b*30 + t)*2]   = st1[t];
    bkt[((size_t)b*30 + t)*2+1] = st2[t];
  }
}

// stage-1 per-segment column max of [x11|x12|x13] (stride 32, coalesced)
__global__ __launch_bounds__(256) void k_max1(
    const float* __restrict__ x11, const float* __restrict__ x12,
    const float* __restrict__ x13, float* __restrict__ pm)
{
  __shared__ float red[256];
  int t = threadIdx.x, c = t & 31, rg = t >> 5;
  int b = blockIdx.x >> 3, seg = blockIdx.x & 7;
  int r0 = b*2048 + seg*256;
  const float* srcs[3] = {x11, x12, x13};
  for (int a = 0; a < 3; ++a) {
    const float* p = srcs[a] + (size_t)(r0+rg)*32 + c;
    float m = -3.4e38f;
    for (int it = 0; it < 32; ++it) m = fmaxf(m, p[it*256]);
    red[t] = m;
    __syncthreads();
    if (t < 30) {
      float mm = red[t];
      for (int g = 1; g < 8; ++g) mm = fmaxf(mm, red[g*32+t]);
      pm[(size_t)(b*8+seg)*90 + a*30 + t] = mm;
    }
    __syncthreads();
  }
}

// finish maxes: x1out from partials; x2out from x21/x22/BN(Z23) (stride 30)
__global__ __launch_bounds__(128) void k_max2(
    const float* __restrict__ pm, const float* __restrict__ x21,
    const float* __restrict__ x22, const float* __restrict__ Z23,
    const float* __restrict__ ac23, float* __restrict__ x1out, float* __restrict__ x2out)
{
  int b = blockIdx.x, c = threadIdx.x;
  if (c >= 90) return;
  float m = -3.4e38f;
  for (int s = 0; s < 8; ++s) m = fmaxf(m, pm[(size_t)(b*8+s)*90 + c]);
  x1out[b*90+c] = m;
  float m2 = -3.4e38f;
  int cc = c % 30;
  for (int i = 0; i < 100; ++i) {
    float v;
    if (c < 30) v = x21[(size_t)b*3000 + i*30 + cc];
    else if (c < 60) v = x22[(size_t)b*3000 + i*30 + cc];
    else v = ac23[cc]*Z23[(size_t)b*3000 + i*30 + cc] + ac23[30+cc];
    m2 = fmaxf(m2, v);
  }
  x2out[b*90+c] = m2;
}

__global__ __launch_bounds__(512) void k_mlp(
    const float* __restrict__ x1out, const float* __restrict__ x2out,
    const float* __restrict__ W1, const float* __restrict__ b1,
    const float* __restrict__ W2, const float* __restrict__ b2,
    float* __restrict__ out)
{
  __shared__ float hh[400];
  int t = threadIdx.x;
  if (t < 400) {
    int b = t/50, j = t%50;
    float acc = b1[j];
    for (int k = 0; k < 90; ++k) acc += x1out[b*90+k]*W1[k*50+j];
    for (int k = 0; k < 90; ++k) acc += x2out[b*90+k]*W1[(90+k)*50+j];
    hh[t] = fmaxf(acc, 0.f);
  }
  __syncthreads();
  if (t < 48) {
    int b = t/6, o = t%6;
    float acc = b2[o];
    for (int j = 0; j < 50; ++j) acc += hh[b*50+j]*W2[j*6+o];
    out[b*6+o] = acc;
  }
}

// ---------------- launcher ----------------
extern "C" void kernel_launch(void* const* d_in, const int* in_sizes, int n_in,
                              void* d_out, int out_size, void* d_ws, size_t ws_size,
                              hipStream_t stream)
{
  const float* x    = (const float*)d_in[0];
  const float* adj  = (const float*)d_in[1];
  const float* Win  = (const float*)d_in[2];
  const float* W3030= (const float*)d_in[3];
  const float* Wp13 = (const float*)d_in[4];
  // d_in[5]=b30, d_in[6]=b100: cancel through training-mode BN -> unused
  const float* Wfc  = (const float*)d_in[7];
  const float* bfc  = (const float*)d_in[8];
  const float* W1   = (const float*)d_in[9];
  const float* b1   = (const float*)d_in[10];
  const float* W2   = (const float*)d_in[11];
  const float* b2   = (const float*)d_in[12];
  const float* g30  = (const float*)d_in[13];
  const float* be30 = (const float*)d_in[14];
  const float* g100 = (const float*)d_in[15];
  const float* be100= (const float*)d_in[16];
  float* out = (float*)d_out;

  float* wsf = (float*)d_ws;
  float* bktL1 = wsf + OF_BKT_L1;
  float* bktL2 = wsf + OF_BKT_L2;
  float* bktL3 = wsf + OF_BKT_L3;
  float* bktS2a = wsf + OF_BKT_S2A;
  float* bktS2b = wsf + OF_BKT_S2B;
  float* bktS2c = wsf + OF_BKT_S2C;
  float* p1x   = wsf + OF_P1X;
  float* p1adj = wsf + OF_P1ADJ;
  float* ellv  = wsf + OF_ELLV;
  unsigned short* ellc = (unsigned short*)(wsf + OF_ELLC);
  int*   rowlen = (int*)(wsf + OF_ROWLEN);
  float* dinvw = wsf + OF_DINVW;
  float* dinvb = wsf + OF_DINVB;
  float* Hw = wsf + OF_HW;
  float* Hb = wsf + OF_HB;      // later: softmax S
  float* Zw = wsf + OF_ZW;
  float* Zb = wsf + OF_ZB;      // later: As = adj@s
  float* x11 = wsf + OF_X11;
  float* x12 = wsf + OF_X12;
  float* x13 = wsf + OF_X13;
  float* s11 = wsf + OF_S11;
  float* s12 = wsf + OF_S12;
  float* pp  = wsf + OF_S11;    // pool partials reuse s11+s12 (dead after fcpool)
  float* acw1 = wsf + OF_AC + 0;
  float* acb1 = wsf + OF_AC + 256;
  float* acw2 = wsf + OF_AC + 512;
  float* acb2 = wsf + OF_AC + 768;
  float* acw3 = wsf + OF_AC + 1024;
  float* acb3 = wsf + OF_AC + 1280;
  float* acs1 = wsf + OF_AC + 1536;
  float* acs2 = wsf + OF_AC + 1792;
  float* acs3 = wsf + OF_AC + 2048;
  float* A2  = wsf + OF_A2;
  float* Z21 = wsf + OF_Z21;
  float* Z22 = wsf + OF_Z22;
  float* Z23 = wsf + OF_Z23;
  float* x21 = wsf + OF_X21;
  float* x22 = wsf + OF_X22;
  float* partmax = wsf + OF_PARTMAX;
  float* x1out = wsf + OF_X1OUT;
  float* x2out = wsf + OF_X2OUT;

  k_build_ell<<<RTOT, 256, 0, stream>>>(adj, ellv, ellc, rowlen, dinvw, dinvb);
  k_h1<<<RTOT*32/256, 256, 0, stream>>>(x, Win, dinvw, dinvb, Hw, Hb);

  // level 1
  k_spmm32<true><<<RTOT*8/256, 256, 0, stream>>>(Hw, Hb, ellv, ellc, rowlen, dinvw, dinvb, Zw, Zb);
  k_stats32<<<64, 256, 0, stream>>>(Zw, Zb, bktL1, 60);
  k_finalize<<<1, 256, 0, stream>>>(bktL1, 64, 60, 16384.f, g30+0,  be30+0,  30, acw1, g30+90,  be30+90,  30, acb1);
  k_apply_gemm<8,32><<<RTOT*16/256, 256, 0, stream>>>(Zw, acw1, x11, W3030+0, Hw, dinvw, Zb, acb1, s11, W3030+2*900, Hb, dinvb);

  // level 2
  k_spmm32<true><<<RTOT*8/256, 256, 0, stream>>>(Hw, Hb, ellv, ellc, rowlen, dinvw, dinvb, Zw, Zb);
  k_stats32<<<64, 256, 0, stream>>>(Zw, Zb, bktL2, 60);
  k_finalize<<<1, 256, 0, stream>>>(bktL2, 64, 60, 16384.f, g30+30, be30+30, 30, acw2, g30+120, be30+120, 30, acb2);
  k_apply_gemm<25,100><<<RTOT*33/256, 256, 0, stream>>>(Zw, acw2, x12, W3030+900, Hw, dinvw, Zb, acb2, s12, Wp13, Hb, dinvb);

  // level 3
  k_spmm32<false><<<RTOT*8/256, 256, 0, stream>>>(Hw, nullptr, ellv, ellc, rowlen, dinvw, nullptr, Zw, nullptr);
  k_spmm100<false,true,true><<<RTOT*25/256, 256, 0, stream>>>(Hb, ellv, ellc, rowlen, dinvb, Zb);
  k_stats_l3<<<64, 256, 0, stream>>>(Zw, Zb, bktL3);
  k_finalize<<<1, 256, 0, stream>>>(bktL3, 64, 130, 16384.f, g30+60, be30+60, 30, acw3, g100, be100, 100, acb3);

  // pooling assignment
  k_fcpool<<<256, 256, 0, stream>>>(Zw, acw3, Zb, acb3, s11, s12, Wfc, bfc, x13, Hb /* S */);
  k_softmax<<<4096, 256, 0, stream>>>(Hb);
  k_spmm100<true,false,false><<<RTOT*25/256, 256, 0, stream>>>(Hb, ellv, ellc, rowlen, nullptr, Zb /* As */);
  k_pool_part<<<64, 256, 0, stream>>>(Hb, x13, Zb, pp);
  k_pool_reduce<<<(BATCH*13000 + 255)/256, 256, 0, stream>>>(pp, p1x, p1adj);
  k_norm_a2<<<BATCH, 256, 0, stream>>>(p1adj, A2);

  // stage 2
  k_s2layer<<<BATCH, 256, 0, stream>>>(p1x, nullptr, nullptr, nullptr, W3030+3*900, A2, Z21, bktS2a);
  k_finalize<<<1, 256, 0, stream>>>(bktS2a, 8, 30, 800.f, g30+150, be30+150, 30, acs1, nullptr, nullptr, 0, nullptr);
  k_s2layer<<<BATCH, 256, 0, stream>>>(nullptr, Z21, acs1, x21, W3030+4*900, A2, Z22, bktS2b);
  k_finalize<<<1, 256, 0, stream>>>(bktS2b, 8, 30, 800.f, g30+180, be30+180, 30, acs2, nullptr, nullptr, 0, nullptr);
  k_s2layer<<<BATCH, 256, 0, stream>>>(nullptr, Z22, acs2, x22, W3030+5*900, A2, Z23, bktS2c);
  k_finalize<<<1, 256, 0, stream>>>(bktS2c, 8, 30, 800.f, g30+210, be30+210, 30, acs3, nullptr, nullptr, 0, nullptr);

  // readout
  k_max1<<<64, 256, 0, stream>>>(x11, x12, x13, partmax);
  k_max2<<<BATCH, 128, 0, stream>>>(partmax, x21, x22, Z23, acs3, x1out, x2out);
  k_mlp<<<1, 512, 0, stream>>>(x1out, x2out, W1, b1, W2, b2, out);
}